// Round 4
// baseline (335.321 us; speedup 1.0000x reference)
//
#include <hip/hip_runtime.h>

// ---------------------------------------------------------------------------
// 2-layer GAT (H=2, D=64, Fin=128) on MI355X.
// bf16 MFMA GEMMs (fused attn-coeff epilogue, in-kernel f32->bf16 cast),
// packed-bf16 Z, single-pass edge softmax aggregation with 16-lane x 4-edge
// group gathers (dwordx4 per lane) and packed-f32 accumulation.
// ---------------------------------------------------------------------------

typedef __attribute__((ext_vector_type(8))) short short8;
typedef __attribute__((ext_vector_type(8))) unsigned short ushort8;
typedef __attribute__((ext_vector_type(4))) float f32x4;
typedef __attribute__((ext_vector_type(2))) float f32x2;

__device__ inline unsigned int f2bf(float x) {
    unsigned int u = __builtin_bit_cast(unsigned int, x);
    return (u + 0x7fffu + ((u >> 16) & 1u)) >> 16;   // RNE
}
__device__ inline float bflo(unsigned int u) {       // low bf16 -> f32
    return __builtin_bit_cast(float, u << 16);
}
__device__ inline float bfhi(unsigned int u) {       // high bf16 -> f32
    return __builtin_bit_cast(float, u & 0xffff0000u);
}

// ---------------- init: W transposes + zero counts -------------------------
__global__ __launch_bounds__(256) void init_small(
    const float* __restrict__ W1, unsigned short* __restrict__ W1t,
    const float* __restrict__ W2, unsigned short* __restrict__ W2t,
    int* __restrict__ counts, int N) {
    int i = blockIdx.x * 256 + threadIdx.x;
    if (i < 128 * 128) {  // W1[k][c] -> W1t[c][k]
        int k = i >> 7, c = i & 127;
        W1t[c * 128 + k] = (unsigned short)f2bf(W1[i]);
        return;
    }
    int l = i - 128 * 128;
    if (l < 64 * 128) {   // W2[k][c] -> W2t[c][k]
        int k = l >> 7, c = l & 127;
        W2t[c * 64 + k] = (unsigned short)f2bf(W2[l]);
        return;
    }
    int q = l - 64 * 128;
    if (q < N) counts[q] = 0;
}

// ---------------- CSR build ----------------
__global__ __launch_bounds__(256) void count_deg(const int* __restrict__ dst,
                                                 int* __restrict__ counts, int E) {
    int i = blockIdx.x * blockDim.x + threadIdx.x;
    if (i < E) atomicAdd(&counts[dst[i]], 1);
}

__global__ __launch_bounds__(1024) void scan1(const int* __restrict__ counts,
                                              int* __restrict__ excl,
                                              int* __restrict__ bsum, int N) {
    __shared__ int s[1024];
    int tid = threadIdx.x;
    int gid = blockIdx.x * 1024 + tid;
    int v = (gid < N) ? counts[gid] : 0;
    s[tid] = v;
    __syncthreads();
    for (int off = 1; off < 1024; off <<= 1) {
        int t = (tid >= off) ? s[tid - off] : 0;
        __syncthreads();
        s[tid] += t;
        __syncthreads();
    }
    if (gid < N) excl[gid] = s[tid] - v;
    if (tid == 1023) bsum[blockIdx.x] = s[1023];
}

__global__ __launch_bounds__(1024) void scan2(int* __restrict__ bsum, int nb) {
    __shared__ int s[1024];
    int tid = threadIdx.x;
    int v = (tid < nb) ? bsum[tid] : 0;
    s[tid] = v;
    __syncthreads();
    for (int off = 1; off < 1024; off <<= 1) {
        int t = (tid >= off) ? s[tid - off] : 0;
        __syncthreads();
        s[tid] += t;
        __syncthreads();
    }
    if (tid < nb) bsum[tid] = s[tid] - v;
}

__global__ __launch_bounds__(1024) void scan3(int* __restrict__ excl_inout,
                                              const int* __restrict__ bsum,
                                              int* __restrict__ cursor, int N, int E) {
    int gid = blockIdx.x * 1024 + threadIdx.x;
    if (gid < N) {
        int v = excl_inout[gid] + bsum[blockIdx.x];
        excl_inout[gid] = v;
        cursor[gid] = v;
    }
    if (gid == 0) excl_inout[N] = E;
}

__global__ __launch_bounds__(256) void fill_edges(const int* __restrict__ src,
                                                  const int* __restrict__ dst,
                                                  int* __restrict__ cursor,
                                                  int* __restrict__ esrc, int E) {
    int i = blockIdx.x * blockDim.x + threadIdx.x;
    if (i < E) {
        int p = atomicAdd(&cursor[dst[i]], 1);
        esrc[p] = src[i];
    }
}

// ---------------- MFMA GEMM + fused attn-coefficient epilogue --------------
// SRC32: X is f32 (cast to bf16 during LDS staging); else X is bf16.
template <int K, bool SRC32>
__global__ __launch_bounds__(256) void gemm_mfma(
    const void* __restrict__ Xv, const unsigned short* __restrict__ Wt,
    const float* __restrict__ al, const float* __restrict__ ar,
    unsigned int* __restrict__ Zg, float2* __restrict__ el2,
    float2* __restrict__ er2, int N) {
    constexpr int LDX = K + 8;
    __shared__ unsigned short Ws[128 * LDX];
    __shared__ unsigned short Xs[64 * LDX];
    const int tid = threadIdx.x;
    const int row0 = blockIdx.x * 64;

    constexpr int KC = K / 8;
    for (int i = tid; i < 128 * KC; i += 256) {
        int r = i / KC, c8 = i % KC;
        ushort8 v = *(const ushort8*)&Wt[r * K + c8 * 8];
        *(ushort8*)&Ws[r * LDX + c8 * 8] = v;
    }
    for (int i = tid; i < 64 * KC; i += 256) {
        int r = i / KC, c8 = i % KC;
        int gr = row0 + r;
        int sr = (gr < N) ? gr : 0;
        if constexpr (SRC32) {
            const float4* fp = (const float4*)((const float*)Xv + (size_t)sr * K + c8 * 8);
            float4 v0 = fp[0], v1 = fp[1];
            ushort8 o = {(unsigned short)f2bf(v0.x), (unsigned short)f2bf(v0.y),
                         (unsigned short)f2bf(v0.z), (unsigned short)f2bf(v0.w),
                         (unsigned short)f2bf(v1.x), (unsigned short)f2bf(v1.y),
                         (unsigned short)f2bf(v1.z), (unsigned short)f2bf(v1.w)};
            *(ushort8*)&Xs[r * LDX + c8 * 8] = o;
        } else {
            ushort8 v = *(const ushort8*)((const unsigned short*)Xv + (size_t)sr * K + c8 * 8);
            *(ushort8*)&Xs[r * LDX + c8 * 8] = v;
        }
    }
    __syncthreads();

    const int wv = tid >> 6, lane = tid & 63;
    const int m = lane & 15, q = lane >> 4;

    f32x4 acc[8];
#pragma unroll
    for (int t = 0; t < 8; ++t) {
        acc[t][0] = 0.f; acc[t][1] = 0.f; acc[t][2] = 0.f; acc[t][3] = 0.f;
    }

    const int arow = wv * 16 + m;
#pragma unroll
    for (int k0 = 0; k0 < K; k0 += 32) {
        short8 a = *(const short8*)&Xs[arow * LDX + k0 + q * 8];
#pragma unroll
        for (int t = 0; t < 8; ++t) {
            short8 b = *(const short8*)&Ws[(t * 16 + m) * LDX + k0 + q * 8];
            acc[t] = __builtin_amdgcn_mfma_f32_16x16x32_bf16(a, b, acc[t], 0, 0, 0);
        }
    }

    // acc[t][r] = Z[row0 + wv*16 + q*4 + r][t*16 + m]
    const int rbase = row0 + wv * 16 + q * 4;
#pragma unroll
    for (int t = 0; t < 4; ++t) {
#pragma unroll
        for (int r = 0; r < 4; ++r) {
            int gr = rbase + r;
            if (gr < N) {
                unsigned int z0 = f2bf(acc[t][r]);
                unsigned int z1 = f2bf(acc[t + 4][r]);
                Zg[(size_t)gr * 64 + t * 16 + m] = z0 | (z1 << 16);
            }
        }
    }

    // fused attn coefficients (al[64 + i] for head1 maps to same table index)
    float alv[8], arv[8];
#pragma unroll
    for (int t = 0; t < 8; ++t) {
        alv[t] = al[t * 16 + m];
        arv[t] = ar[t * 16 + m];
    }
#pragma unroll
    for (int r = 0; r < 4; ++r) {
        float pel0 = 0.f, pel1 = 0.f, per0 = 0.f, per1 = 0.f;
#pragma unroll
        for (int t = 0; t < 4; ++t) {
            pel0 += acc[t][r] * alv[t];
            per0 += acc[t][r] * arv[t];
            pel1 += acc[t + 4][r] * alv[t + 4];
            per1 += acc[t + 4][r] * arv[t + 4];
        }
#pragma unroll
        for (int off = 1; off < 16; off <<= 1) {
            pel0 += __shfl_xor(pel0, off);
            pel1 += __shfl_xor(pel1, off);
            per0 += __shfl_xor(per0, off);
            per1 += __shfl_xor(per1, off);
        }
        int gr = rbase + r;
        if (m == 0 && gr < N) {
            el2[gr] = make_float2(pel0, pel1);
            er2[gr] = make_float2(per0, per1);
        }
    }
}

// ---------------- aggregate: single-pass softmax + group-gather -------------
// One wave per dst node; 4 groups x 16 lanes; group g handles edge j+g with
// dwordx4 row loads (16 lanes x 16 B = 256 B row). Lane li holds features
// f = 4*li..4*li+3 (both heads packed per dword).
__global__ __launch_bounds__(256) void aggregate(
    const unsigned int* __restrict__ Zg, const float2* __restrict__ el2,
    const float2* __restrict__ er2, const int* __restrict__ row_start,
    const int* __restrict__ esrc, const float* __restrict__ bias,
    const float* __restrict__ gamma, const float* __restrict__ beta,
    unsigned short* __restrict__ out_bf, float* __restrict__ out_f,
    int N, int do_ln) {
    int wv = (blockIdx.x * blockDim.x + threadIdx.x) >> 6;
    int lane = threadIdx.x & 63;
    if (wv >= N) return;
    const int g = lane >> 4, li = lane & 15;
    int s0 = row_start[wv], s1 = row_start[wv + 1];
    float2 er = er2[wv];

    f32x2 acc[4] = {{0.f, 0.f}, {0.f, 0.f}, {0.f, 0.f}, {0.f, 0.f}};
    float dsum0 = 0.f, dsum1 = 0.f;

    for (int base = s0; base < s1; base += 64) {
        int idx = base + lane;
        int sv = 0;
        float w0 = 0.f, w1 = 0.f;
        if (idx < s1) {
            sv = esrc[idx];
            float2 elv = el2[sv];
            float e0 = elv.x + er.x;
            e0 = e0 > 0.f ? e0 : 0.2f * e0;
            float e1 = elv.y + er.y;
            e1 = e1 > 0.f ? e1 : 0.2f * e1;
            w0 = __expf(e0);
            w1 = __expf(e1);
        }
        dsum0 += w0;
        dsum1 += w1;
        int mm = min(64, s1 - base);
        // group g takes edge j+g; inactive groups have w==0 (sv==0 row load is
        // harmless & L2-hot), so no divergence in the loop body.
        for (int j = 0; j < mm; j += 4) {
            int e = j + g;
            int sve = __shfl(sv, e);
            float we0 = __shfl(w0, e);
            float we1 = __shfl(w1, e);
            const uint4 u = *(const uint4*)(Zg + (((unsigned)sve << 6) + li * 4));
            f32x2 w2 = {we0, we1};
            f32x2 z0 = {bflo(u.x), bfhi(u.x)};
            f32x2 z1 = {bflo(u.y), bfhi(u.y)};
            f32x2 z2 = {bflo(u.z), bfhi(u.z)};
            f32x2 z3 = {bflo(u.w), bfhi(u.w)};
            acc[0] += w2 * z0;
            acc[1] += w2 * z1;
            acc[2] += w2 * z2;
            acc[3] += w2 * z3;
        }
    }

    // reduce accumulators across the 4 groups (xor 16, 32 -> all lanes hold sum)
#pragma unroll
    for (int k = 0; k < 4; ++k) {
        f32x2 t;
        t[0] = __shfl_xor(acc[k][0], 16);
        t[1] = __shfl_xor(acc[k][1], 16);
        acc[k] += t;
        t[0] = __shfl_xor(acc[k][0], 32);
        t[1] = __shfl_xor(acc[k][1], 32);
        acc[k] += t;
    }
    // denominator reduce over all 64 lanes
#pragma unroll
    for (int off = 1; off < 64; off <<= 1) {
        dsum0 += __shfl_xor(dsum0, off);
        dsum1 += __shfl_xor(dsum1, off);
    }
    float inv0 = dsum0 > 0.f ? 1.f / dsum0 : 0.f;
    float inv1 = dsum1 > 0.f ? 1.f / dsum1 : 0.f;

    float4 blo = *(const float4*)&bias[li * 4];
    float4 bhi = *(const float4*)&bias[64 + li * 4];
    float m0[4];
    m0[0] = (acc[0][0] * inv0 + acc[0][1] * inv1) * 0.5f + 0.5f * (blo.x + bhi.x);
    m0[1] = (acc[1][0] * inv0 + acc[1][1] * inv1) * 0.5f + 0.5f * (blo.y + bhi.y);
    m0[2] = (acc[2][0] * inv0 + acc[2][1] * inv1) * 0.5f + 0.5f * (blo.z + bhi.z);
    m0[3] = (acc[3][0] * inv0 + acc[3][1] * inv1) * 0.5f + 0.5f * (blo.w + bhi.w);

    if (do_ln) {
        float s = m0[0] + m0[1] + m0[2] + m0[3];
#pragma unroll
        for (int off = 1; off < 16; off <<= 1) s += __shfl_xor(s, off);
        float mu = s * (1.f / 64.f);
        float d0 = m0[0] - mu, d1 = m0[1] - mu, d2 = m0[2] - mu, d3 = m0[3] - mu;
        float v = d0 * d0 + d1 * d1 + d2 * d2 + d3 * d3;
#pragma unroll
        for (int off = 1; off < 16; off <<= 1) v += __shfl_xor(v, off);
        float rstd = rsqrtf(v * (1.f / 64.f) + 1e-5f);
        if (g == 0) {
            float4 g4 = *(const float4*)&gamma[li * 4];
            float4 be4 = *(const float4*)&beta[li * 4];
            float y0 = d0 * rstd * g4.x + be4.x;
            float y1 = d1 * rstd * g4.y + be4.y;
            float y2 = d2 * rstd * g4.z + be4.z;
            float y3 = d3 * rstd * g4.w + be4.w;
            y0 = y0 > 0.f ? y0 : 0.f;
            y1 = y1 > 0.f ? y1 : 0.f;
            y2 = y2 > 0.f ? y2 : 0.f;
            y3 = y3 > 0.f ? y3 : 0.f;
            ushort4 o = {(unsigned short)f2bf(y0), (unsigned short)f2bf(y1),
                         (unsigned short)f2bf(y2), (unsigned short)f2bf(y3)};
            *(ushort4*)&out_bf[(size_t)wv * 64 + li * 4] = o;
        }
    } else {
        if (g == 0) {
            *(float4*)&out_f[(size_t)wv * 64 + li * 4] =
                make_float4(m0[0], m0[1], m0[2], m0[3]);
        }
    }
}

// ---------------------------------------------------------------------------
static inline char* align_up(char* p, size_t a) {
    return (char*)(((uintptr_t)p + a - 1) & ~(uintptr_t)(a - 1));
}

extern "C" void kernel_launch(void* const* d_in, const int* in_sizes, int n_in,
                              void* d_out, int out_size, void* d_ws, size_t ws_size,
                              hipStream_t stream) {
    const float* feat = (const float*)d_in[0];
    const int* src = (const int*)d_in[1];
    const int* dst = (const int*)d_in[2];
    const float* W1 = (const float*)d_in[3];
    const float* al1 = (const float*)d_in[4];
    const float* ar1 = (const float*)d_in[5];
    const float* b1 = (const float*)d_in[6];
    const float* gamma1 = (const float*)d_in[7];
    const float* beta1 = (const float*)d_in[8];
    const float* W2 = (const float*)d_in[9];
    const float* al2 = (const float*)d_in[10];
    const float* ar2 = (const float*)d_in[11];
    const float* b2 = (const float*)d_in[12];

    const int N = in_sizes[0] / 128;
    const int E = in_sizes[1];

    char* p = (char*)d_ws;
    unsigned int* Zg = (unsigned int*)p;            p += (size_t)N * 64 * 4;
    float2* el2 = (float2*)p;                       p += (size_t)N * 8;
    float2* er2 = (float2*)p;                       p += (size_t)N * 8;
    int* counts = (int*)p;                          p += (size_t)N * 4;
    int* row_start = (int*)p;                       p += (size_t)(N + 1) * 4;
    int* cursor = (int*)p;                          p += (size_t)N * 4;
    int* bsum = (int*)p;                            p += 1024 * 4;
    int* esrc = (int*)p;                            p += (size_t)E * 4;
    p = align_up(p, 64);
    unsigned short* hb = (unsigned short*)p;        p += (size_t)N * 64 * 2;
    p = align_up(p, 64);
    unsigned short* W1t = (unsigned short*)p;       p += 128 * 128 * 2;
    unsigned short* W2t = (unsigned short*)p;       p += 128 * 64 * 2;

    const int nb = (N + 1023) / 1024;
    const int init_work = 128 * 128 + 64 * 128 + N;

    init_small<<<(init_work + 255) / 256, 256, 0, stream>>>(W1, W1t, W2, W2t, counts, N);
    count_deg<<<(E + 255) / 256, 256, 0, stream>>>(dst, counts, E);
    scan1<<<nb, 1024, 0, stream>>>(counts, row_start, bsum, N);
    scan2<<<1, 1024, 0, stream>>>(bsum, nb);
    scan3<<<nb, 1024, 0, stream>>>(row_start, bsum, cursor, N, E);
    fill_edges<<<(E + 255) / 256, 256, 0, stream>>>(src, dst, cursor, esrc, E);

    // layer 0
    gemm_mfma<128, true><<<(N + 63) / 64, 256, 0, stream>>>(feat, W1t, al1, ar1,
                                                            Zg, el2, er2, N);
    aggregate<<<(N + 3) / 4, 256, 0, stream>>>(Zg, el2, er2, row_start, esrc, b1,
                                               gamma1, beta1, hb, nullptr, N, 1);

    // layer 1
    gemm_mfma<64, false><<<(N + 63) / 64, 256, 0, stream>>>(hb, W2t, al2, ar2,
                                                            Zg, el2, er2, N);
    aggregate<<<(N + 3) / 4, 256, 0, stream>>>(Zg, el2, er2, row_start, esrc, b2,
                                               nullptr, nullptr, nullptr, (float*)d_out, N, 0);
}

// Round 5
// 312.591 us; speedup vs baseline: 1.0727x; 1.0727x over previous
//
#include <hip/hip_runtime.h>

// ---------------------------------------------------------------------------
// 2-layer GAT (H=2, D=64, Fin=128) on MI355X.
// bf16 MFMA GEMMs (fused attn-coeff epilogue), packed-bf16 Z rows,
// edge-parallel weight precompute (int4 {src,w0,w1,-} per CSR slot),
// group-per-node aggregation: 16-lane groups, 4 nodes/wave, 4x-unrolled
// dwordx4 gathers with addresses available up front (high MLP).
// ---------------------------------------------------------------------------

typedef __attribute__((ext_vector_type(8))) short short8;
typedef __attribute__((ext_vector_type(8))) unsigned short ushort8;
typedef __attribute__((ext_vector_type(4))) float f32x4;
typedef __attribute__((ext_vector_type(2))) float f32x2;

__device__ inline unsigned int f2bf(float x) {
    unsigned int u = __builtin_bit_cast(unsigned int, x);
    return (u + 0x7fffu + ((u >> 16) & 1u)) >> 16;   // RNE
}
__device__ inline float bflo(unsigned int u) {
    return __builtin_bit_cast(float, u << 16);
}
__device__ inline float bfhi(unsigned int u) {
    return __builtin_bit_cast(float, u & 0xffff0000u);
}
__device__ inline float i2f(int v) { return __builtin_bit_cast(float, v); }

// ---------------- init: W transposes + zero counts -------------------------
__global__ __launch_bounds__(256) void init_small(
    const float* __restrict__ W1, unsigned short* __restrict__ W1t,
    const float* __restrict__ W2, unsigned short* __restrict__ W2t,
    int* __restrict__ counts, int N) {
    int i = blockIdx.x * 256 + threadIdx.x;
    if (i < 128 * 128) {
        int k = i >> 7, c = i & 127;
        W1t[c * 128 + k] = (unsigned short)f2bf(W1[i]);
        return;
    }
    int l = i - 128 * 128;
    if (l < 64 * 128) {
        int k = l >> 7, c = l & 127;
        W2t[c * 64 + k] = (unsigned short)f2bf(W2[l]);
        return;
    }
    int q = l - 64 * 128;
    if (q < N) counts[q] = 0;
}

// ---------------- CSR build ----------------
__global__ __launch_bounds__(256) void count_deg(const int* __restrict__ dst,
                                                 int* __restrict__ counts, int E) {
    int i = blockIdx.x * blockDim.x + threadIdx.x;
    if (i < E) atomicAdd(&counts[dst[i]], 1);
}

__global__ __launch_bounds__(1024) void scan1(const int* __restrict__ counts,
                                              int* __restrict__ excl,
                                              int* __restrict__ bsum, int N) {
    __shared__ int s[1024];
    int tid = threadIdx.x;
    int gid = blockIdx.x * 1024 + tid;
    int v = (gid < N) ? counts[gid] : 0;
    s[tid] = v;
    __syncthreads();
    for (int off = 1; off < 1024; off <<= 1) {
        int t = (tid >= off) ? s[tid - off] : 0;
        __syncthreads();
        s[tid] += t;
        __syncthreads();
    }
    if (gid < N) excl[gid] = s[tid] - v;
    if (tid == 1023) bsum[blockIdx.x] = s[1023];
}

__global__ __launch_bounds__(1024) void scan2(int* __restrict__ bsum, int nb) {
    __shared__ int s[1024];
    int tid = threadIdx.x;
    int v = (tid < nb) ? bsum[tid] : 0;
    s[tid] = v;
    __syncthreads();
    for (int off = 1; off < 1024; off <<= 1) {
        int t = (tid >= off) ? s[tid - off] : 0;
        __syncthreads();
        s[tid] += t;
        __syncthreads();
    }
    if (tid < nb) bsum[tid] = s[tid] - v;
}

__global__ __launch_bounds__(1024) void scan3(int* __restrict__ excl_inout,
                                              const int* __restrict__ bsum,
                                              int* __restrict__ cursor, int N, int E) {
    int gid = blockIdx.x * 1024 + threadIdx.x;
    if (gid < N) {
        int v = excl_inout[gid] + bsum[blockIdx.x];
        excl_inout[gid] = v;
        cursor[gid] = v;
    }
    if (gid == 0) excl_inout[N] = E;
}

__global__ __launch_bounds__(256) void fill_edges(const int* __restrict__ src,
                                                  const int* __restrict__ dst,
                                                  int* __restrict__ cursor,
                                                  int* __restrict__ esrc,
                                                  int* __restrict__ edst, int E) {
    int i = blockIdx.x * blockDim.x + threadIdx.x;
    if (i < E) {
        int d = dst[i];
        int p = atomicAdd(&cursor[d], 1);
        esrc[p] = src[i];
        edst[p] = d;
    }
}

// ---------------- MFMA GEMM + fused attn-coefficient epilogue --------------
template <int K, bool SRC32>
__global__ __launch_bounds__(256) void gemm_mfma(
    const void* __restrict__ Xv, const unsigned short* __restrict__ Wt,
    const float* __restrict__ al, const float* __restrict__ ar,
    unsigned int* __restrict__ Zg, float2* __restrict__ el2,
    float2* __restrict__ er2, int N) {
    constexpr int LDX = K + 8;
    __shared__ unsigned short Ws[128 * LDX];
    __shared__ unsigned short Xs[64 * LDX];
    const int tid = threadIdx.x;
    const int row0 = blockIdx.x * 64;

    constexpr int KC = K / 8;
    for (int i = tid; i < 128 * KC; i += 256) {
        int r = i / KC, c8 = i % KC;
        ushort8 v = *(const ushort8*)&Wt[r * K + c8 * 8];
        *(ushort8*)&Ws[r * LDX + c8 * 8] = v;
    }
    for (int i = tid; i < 64 * KC; i += 256) {
        int r = i / KC, c8 = i % KC;
        int gr = row0 + r;
        int sr = (gr < N) ? gr : 0;
        if constexpr (SRC32) {
            const float4* fp = (const float4*)((const float*)Xv + (size_t)sr * K + c8 * 8);
            float4 v0 = fp[0], v1 = fp[1];
            ushort8 o = {(unsigned short)f2bf(v0.x), (unsigned short)f2bf(v0.y),
                         (unsigned short)f2bf(v0.z), (unsigned short)f2bf(v0.w),
                         (unsigned short)f2bf(v1.x), (unsigned short)f2bf(v1.y),
                         (unsigned short)f2bf(v1.z), (unsigned short)f2bf(v1.w)};
            *(ushort8*)&Xs[r * LDX + c8 * 8] = o;
        } else {
            ushort8 v = *(const ushort8*)((const unsigned short*)Xv + (size_t)sr * K + c8 * 8);
            *(ushort8*)&Xs[r * LDX + c8 * 8] = v;
        }
    }
    __syncthreads();

    const int wv = tid >> 6, lane = tid & 63;
    const int m = lane & 15, q = lane >> 4;

    f32x4 acc[8];
#pragma unroll
    for (int t = 0; t < 8; ++t) {
        acc[t][0] = 0.f; acc[t][1] = 0.f; acc[t][2] = 0.f; acc[t][3] = 0.f;
    }

    const int arow = wv * 16 + m;
#pragma unroll
    for (int k0 = 0; k0 < K; k0 += 32) {
        short8 a = *(const short8*)&Xs[arow * LDX + k0 + q * 8];
#pragma unroll
        for (int t = 0; t < 8; ++t) {
            short8 b = *(const short8*)&Ws[(t * 16 + m) * LDX + k0 + q * 8];
            acc[t] = __builtin_amdgcn_mfma_f32_16x16x32_bf16(a, b, acc[t], 0, 0, 0);
        }
    }

    const int rbase = row0 + wv * 16 + q * 4;
#pragma unroll
    for (int t = 0; t < 4; ++t) {
#pragma unroll
        for (int r = 0; r < 4; ++r) {
            int gr = rbase + r;
            if (gr < N) {
                unsigned int z0 = f2bf(acc[t][r]);
                unsigned int z1 = f2bf(acc[t + 4][r]);
                Zg[(size_t)gr * 64 + t * 16 + m] = z0 | (z1 << 16);
            }
        }
    }

    float alv[8], arv[8];
#pragma unroll
    for (int t = 0; t < 8; ++t) {
        alv[t] = al[t * 16 + m];
        arv[t] = ar[t * 16 + m];
    }
#pragma unroll
    for (int r = 0; r < 4; ++r) {
        float pel0 = 0.f, pel1 = 0.f, per0 = 0.f, per1 = 0.f;
#pragma unroll
        for (int t = 0; t < 4; ++t) {
            pel0 += acc[t][r] * alv[t];
            per0 += acc[t][r] * arv[t];
            pel1 += acc[t + 4][r] * alv[t + 4];
            per1 += acc[t + 4][r] * arv[t + 4];
        }
#pragma unroll
        for (int off = 1; off < 16; off <<= 1) {
            pel0 += __shfl_xor(pel0, off);
            pel1 += __shfl_xor(pel1, off);
            per0 += __shfl_xor(per0, off);
            per1 += __shfl_xor(per1, off);
        }
        int gr = rbase + r;
        if (m == 0 && gr < N) {
            el2[gr] = make_float2(pel0, pel1);
            er2[gr] = make_float2(per0, per1);
        }
    }
}

// ---------------- edge weights: w = exp(leaky(el[src]+er[dst])) ------------
__global__ __launch_bounds__(256) void edge_w(
    const int* __restrict__ esrc, const int* __restrict__ edst,
    const float2* __restrict__ el2, const float2* __restrict__ er2,
    int4* __restrict__ esw, int E) {
    int i = blockIdx.x * blockDim.x + threadIdx.x;
    if (i >= E) return;
    int s = esrc[i], d = edst[i];
    float2 el = el2[s];
    float2 er = er2[d];
    float e0 = el.x + er.x;
    e0 = e0 > 0.f ? e0 : 0.2f * e0;
    float e1 = el.y + er.y;
    e1 = e1 > 0.f ? e1 : 0.2f * e1;
    int4 o;
    o.x = s;
    o.y = __builtin_bit_cast(int, __expf(e0));
    o.z = __builtin_bit_cast(int, __expf(e1));
    o.w = 0;
    esw[i] = o;
}

// ---------------- aggregate: group-per-node gather -------------------------
// 16 nodes/block; 16-lane group per node. Strip-load {src,w0,w1} (dwordx4),
// then 4x-unrolled dwordx4 row gathers; all addresses ready up front.
__global__ __launch_bounds__(256) void aggregate(
    const uint4* __restrict__ Zg4, const int4* __restrict__ esw,
    const int* __restrict__ row_start, const float* __restrict__ bias,
    const float* __restrict__ gamma, const float* __restrict__ beta,
    unsigned short* __restrict__ out_bf, float* __restrict__ out_f,
    int N, int do_ln) {
    const int tid = threadIdx.x;
    const int li = tid & 15;
    const int gb = tid & 48;           // group base lane within wave
    const int node = blockIdx.x * 16 + (tid >> 4);
    const bool valid = node < N;
    const int s0 = valid ? row_start[node] : 0;
    const int s1 = valid ? row_start[node + 1] : 0;

    f32x2 acc[4] = {{0.f, 0.f}, {0.f, 0.f}, {0.f, 0.f}, {0.f, 0.f}};
    float dsum0 = 0.f, dsum1 = 0.f;

    for (int base = s0; base < s1; base += 16) {
        int idx = base + li;
        int4 ew = {0, 0, 0, 0};
        if (idx < s1) ew = esw[idx];
        dsum0 += i2f(ew.y);
        dsum1 += i2f(ew.z);
        const int mm = min(16, s1 - base);
        int e = 0;
        for (; e + 4 <= mm; e += 4) {
            int sa = __shfl(ew.x, gb | e);
            int sb = __shfl(ew.x, gb | (e + 1));
            int sc = __shfl(ew.x, gb | (e + 2));
            int sd = __shfl(ew.x, gb | (e + 3));
            uint4 ua = Zg4[((size_t)(unsigned)sa << 4) + li];
            uint4 ub = Zg4[((size_t)(unsigned)sb << 4) + li];
            uint4 uc = Zg4[((size_t)(unsigned)sc << 4) + li];
            uint4 ud = Zg4[((size_t)(unsigned)sd << 4) + li];
            f32x2 wa = {__shfl(i2f(ew.y), gb | e), __shfl(i2f(ew.z), gb | e)};
            f32x2 wb = {__shfl(i2f(ew.y), gb | (e + 1)), __shfl(i2f(ew.z), gb | (e + 1))};
            f32x2 wc = {__shfl(i2f(ew.y), gb | (e + 2)), __shfl(i2f(ew.z), gb | (e + 2))};
            f32x2 wd = {__shfl(i2f(ew.y), gb | (e + 3)), __shfl(i2f(ew.z), gb | (e + 3))};
            acc[0] += wa * f32x2{bflo(ua.x), bfhi(ua.x)};
            acc[1] += wa * f32x2{bflo(ua.y), bfhi(ua.y)};
            acc[2] += wa * f32x2{bflo(ua.z), bfhi(ua.z)};
            acc[3] += wa * f32x2{bflo(ua.w), bfhi(ua.w)};
            acc[0] += wb * f32x2{bflo(ub.x), bfhi(ub.x)};
            acc[1] += wb * f32x2{bflo(ub.y), bfhi(ub.y)};
            acc[2] += wb * f32x2{bflo(ub.z), bfhi(ub.z)};
            acc[3] += wb * f32x2{bflo(ub.w), bfhi(ub.w)};
            acc[0] += wc * f32x2{bflo(uc.x), bfhi(uc.x)};
            acc[1] += wc * f32x2{bflo(uc.y), bfhi(uc.y)};
            acc[2] += wc * f32x2{bflo(uc.z), bfhi(uc.z)};
            acc[3] += wc * f32x2{bflo(uc.w), bfhi(uc.w)};
            acc[0] += wd * f32x2{bflo(ud.x), bfhi(ud.x)};
            acc[1] += wd * f32x2{bflo(ud.y), bfhi(ud.y)};
            acc[2] += wd * f32x2{bflo(ud.z), bfhi(ud.z)};
            acc[3] += wd * f32x2{bflo(ud.w), bfhi(ud.w)};
        }
        for (; e < mm; ++e) {
            int sa = __shfl(ew.x, gb | e);
            uint4 ua = Zg4[((size_t)(unsigned)sa << 4) + li];
            f32x2 wa = {__shfl(i2f(ew.y), gb | e), __shfl(i2f(ew.z), gb | e)};
            acc[0] += wa * f32x2{bflo(ua.x), bfhi(ua.x)};
            acc[1] += wa * f32x2{bflo(ua.y), bfhi(ua.y)};
            acc[2] += wa * f32x2{bflo(ua.z), bfhi(ua.z)};
            acc[3] += wa * f32x2{bflo(ua.w), bfhi(ua.w)};
        }
    }

    // group-local reductions (16-lane butterflies)
#pragma unroll
    for (int off = 1; off < 16; off <<= 1) {
        dsum0 += __shfl_xor(dsum0, off);
        dsum1 += __shfl_xor(dsum1, off);
    }
    float inv0 = dsum0 > 0.f ? 1.f / dsum0 : 0.f;
    float inv1 = dsum1 > 0.f ? 1.f / dsum1 : 0.f;

    if (!valid) return;

    float4 blo = *(const float4*)&bias[li * 4];
    float4 bhi = *(const float4*)&bias[64 + li * 4];
    float m0[4];
    m0[0] = (acc[0][0] * inv0 + acc[0][1] * inv1) * 0.5f + 0.5f * (blo.x + bhi.x);
    m0[1] = (acc[1][0] * inv0 + acc[1][1] * inv1) * 0.5f + 0.5f * (blo.y + bhi.y);
    m0[2] = (acc[2][0] * inv0 + acc[2][1] * inv1) * 0.5f + 0.5f * (blo.z + bhi.z);
    m0[3] = (acc[3][0] * inv0 + acc[3][1] * inv1) * 0.5f + 0.5f * (blo.w + bhi.w);

    if (do_ln) {
        float s = m0[0] + m0[1] + m0[2] + m0[3];
#pragma unroll
        for (int off = 1; off < 16; off <<= 1) s += __shfl_xor(s, off);
        float mu = s * (1.f / 64.f);
        float d0 = m0[0] - mu, d1 = m0[1] - mu, d2 = m0[2] - mu, d3 = m0[3] - mu;
        float v = d0 * d0 + d1 * d1 + d2 * d2 + d3 * d3;
#pragma unroll
        for (int off = 1; off < 16; off <<= 1) v += __shfl_xor(v, off);
        float rstd = rsqrtf(v * (1.f / 64.f) + 1e-5f);
        float4 g4 = *(const float4*)&gamma[li * 4];
        float4 be4 = *(const float4*)&beta[li * 4];
        float y0 = d0 * rstd * g4.x + be4.x;
        float y1 = d1 * rstd * g4.y + be4.y;
        float y2 = d2 * rstd * g4.z + be4.z;
        float y3 = d3 * rstd * g4.w + be4.w;
        y0 = y0 > 0.f ? y0 : 0.f;
        y1 = y1 > 0.f ? y1 : 0.f;
        y2 = y2 > 0.f ? y2 : 0.f;
        y3 = y3 > 0.f ? y3 : 0.f;
        ushort4 o = {(unsigned short)f2bf(y0), (unsigned short)f2bf(y1),
                     (unsigned short)f2bf(y2), (unsigned short)f2bf(y3)};
        *(ushort4*)&out_bf[(size_t)node * 64 + li * 4] = o;
    } else {
        *(float4*)&out_f[(size_t)node * 64 + li * 4] =
            make_float4(m0[0], m0[1], m0[2], m0[3]);
    }
}

// ---------------------------------------------------------------------------
static inline char* align_up(char* p, size_t a) {
    return (char*)(((uintptr_t)p + a - 1) & ~(uintptr_t)(a - 1));
}

extern "C" void kernel_launch(void* const* d_in, const int* in_sizes, int n_in,
                              void* d_out, int out_size, void* d_ws, size_t ws_size,
                              hipStream_t stream) {
    const float* feat = (const float*)d_in[0];
    const int* src = (const int*)d_in[1];
    const int* dst = (const int*)d_in[2];
    const float* W1 = (const float*)d_in[3];
    const float* al1 = (const float*)d_in[4];
    const float* ar1 = (const float*)d_in[5];
    const float* b1 = (const float*)d_in[6];
    const float* gamma1 = (const float*)d_in[7];
    const float* beta1 = (const float*)d_in[8];
    const float* W2 = (const float*)d_in[9];
    const float* al2 = (const float*)d_in[10];
    const float* ar2 = (const float*)d_in[11];
    const float* b2 = (const float*)d_in[12];

    const int N = in_sizes[0] / 128;
    const int E = in_sizes[1];

    char* p = (char*)d_ws;
    p = align_up(p, 256);
    unsigned int* Zg = (unsigned int*)p;            p += (size_t)N * 64 * 4;
    int4* esw = (int4*)p;                           p += (size_t)E * 16;
    float2* el2 = (float2*)p;                       p += (size_t)N * 8;
    float2* er2 = (float2*)p;                       p += (size_t)N * 8;
    int* counts = (int*)p;                          p += (size_t)N * 4;
    int* row_start = (int*)p;                       p += (size_t)(N + 1) * 4;
    int* cursor = (int*)p;                          p += (size_t)N * 4;
    int* bsum = (int*)p;                            p += 1024 * 4;
    int* esrc = (int*)p;                            p += (size_t)E * 4;
    int* edst = (int*)p;                            p += (size_t)E * 4;
    p = align_up(p, 64);
    unsigned short* hb = (unsigned short*)p;        p += (size_t)N * 64 * 2;
    p = align_up(p, 64);
    unsigned short* W1t = (unsigned short*)p;       p += 128 * 128 * 2;
    unsigned short* W2t = (unsigned short*)p;       p += 128 * 64 * 2;

    const int nb = (N + 1023) / 1024;
    const int init_work = 128 * 128 + 64 * 128 + N;

    init_small<<<(init_work + 255) / 256, 256, 0, stream>>>(W1, W1t, W2, W2t, counts, N);
    count_deg<<<(E + 255) / 256, 256, 0, stream>>>(dst, counts, E);
    scan1<<<nb, 1024, 0, stream>>>(counts, row_start, bsum, N);
    scan2<<<1, 1024, 0, stream>>>(bsum, nb);
    scan3<<<nb, 1024, 0, stream>>>(row_start, bsum, cursor, N, E);
    fill_edges<<<(E + 255) / 256, 256, 0, stream>>>(src, dst, cursor, esrc, edst, E);

    // layer 0
    gemm_mfma<128, true><<<(N + 63) / 64, 256, 0, stream>>>(feat, W1t, al1, ar1,
                                                            Zg, el2, er2, N);
    edge_w<<<(E + 255) / 256, 256, 0, stream>>>(esrc, edst, el2, er2, esw, E);
    aggregate<<<(N + 15) / 16, 256, 0, stream>>>((const uint4*)Zg, esw, row_start,
                                                 b1, gamma1, beta1, hb, nullptr, N, 1);

    // layer 1
    gemm_mfma<64, false><<<(N + 63) / 64, 256, 0, stream>>>(hb, W2t, al2, ar2,
                                                            Zg, el2, er2, N);
    edge_w<<<(E + 255) / 256, 256, 0, stream>>>(esrc, edst, el2, er2, esw, E);
    aggregate<<<(N + 15) / 16, 256, 0, stream>>>((const uint4*)Zg, esw, row_start,
                                                 b2, nullptr, nullptr, nullptr,
                                                 (float*)d_out, N, 0);
}

// Round 6
// 301.430 us; speedup vs baseline: 1.1124x; 1.0370x over previous
//
#include <hip/hip_runtime.h>

// ---------------------------------------------------------------------------
// 2-layer GAT (H=2, D=64, Fin=128) on MI355X.
// bf16 MFMA GEMMs (fused attn-coeff epilogue), packed-bf16 Z rows,
// CSR with src-only edge list (one scattered stream), aggregation with
// 16-lane groups / 4 nodes per wave, inline edge-softmax weights (el2 gather
// + exp off the Zg address chain), 4x-unrolled dwordx4 row gathers.
// ---------------------------------------------------------------------------

typedef __attribute__((ext_vector_type(8))) short short8;
typedef __attribute__((ext_vector_type(8))) unsigned short ushort8;
typedef __attribute__((ext_vector_type(4))) float f32x4;
typedef __attribute__((ext_vector_type(2))) float f32x2;

__device__ inline unsigned int f2bf(float x) {
    unsigned int u = __builtin_bit_cast(unsigned int, x);
    return (u + 0x7fffu + ((u >> 16) & 1u)) >> 16;   // RNE
}
__device__ inline float bflo(unsigned int u) {
    return __builtin_bit_cast(float, u << 16);
}
__device__ inline float bfhi(unsigned int u) {
    return __builtin_bit_cast(float, u & 0xffff0000u);
}

// ---------------- init: W transposes + zero counts -------------------------
__global__ __launch_bounds__(256) void init_small(
    const float* __restrict__ W1, unsigned short* __restrict__ W1t,
    const float* __restrict__ W2, unsigned short* __restrict__ W2t,
    int* __restrict__ counts, int N) {
    int i = blockIdx.x * 256 + threadIdx.x;
    if (i < 128 * 128) {
        int k = i >> 7, c = i & 127;
        W1t[c * 128 + k] = (unsigned short)f2bf(W1[i]);
        return;
    }
    int l = i - 128 * 128;
    if (l < 64 * 128) {
        int k = l >> 7, c = l & 127;
        W2t[c * 64 + k] = (unsigned short)f2bf(W2[l]);
        return;
    }
    int q = l - 64 * 128;
    if (q < N) counts[q] = 0;
}

// ---------------- CSR build ----------------
__global__ __launch_bounds__(256) void count_deg(const int* __restrict__ dst,
                                                 int* __restrict__ counts, int E) {
    int i = blockIdx.x * blockDim.x + threadIdx.x;
    if (i < E) atomicAdd(&counts[dst[i]], 1);
}

__global__ __launch_bounds__(1024) void scan1(const int* __restrict__ counts,
                                              int* __restrict__ excl,
                                              int* __restrict__ bsum, int N) {
    __shared__ int s[1024];
    int tid = threadIdx.x;
    int gid = blockIdx.x * 1024 + tid;
    int v = (gid < N) ? counts[gid] : 0;
    s[tid] = v;
    __syncthreads();
    for (int off = 1; off < 1024; off <<= 1) {
        int t = (tid >= off) ? s[tid - off] : 0;
        __syncthreads();
        s[tid] += t;
        __syncthreads();
    }
    if (gid < N) excl[gid] = s[tid] - v;
    if (tid == 1023) bsum[blockIdx.x] = s[1023];
}

__global__ __launch_bounds__(1024) void scan2(int* __restrict__ bsum, int nb) {
    __shared__ int s[1024];
    int tid = threadIdx.x;
    int v = (tid < nb) ? bsum[tid] : 0;
    s[tid] = v;
    __syncthreads();
    for (int off = 1; off < 1024; off <<= 1) {
        int t = (tid >= off) ? s[tid - off] : 0;
        __syncthreads();
        s[tid] += t;
        __syncthreads();
    }
    if (tid < nb) bsum[tid] = s[tid] - v;
}

__global__ __launch_bounds__(1024) void scan3(int* __restrict__ excl_inout,
                                              const int* __restrict__ bsum,
                                              int* __restrict__ cursor, int N, int E) {
    int gid = blockIdx.x * 1024 + threadIdx.x;
    if (gid < N) {
        int v = excl_inout[gid] + bsum[blockIdx.x];
        excl_inout[gid] = v;
        cursor[gid] = v;
    }
    if (gid == 0) excl_inout[N] = E;
}

__global__ __launch_bounds__(256) void fill_edges(const int* __restrict__ src,
                                                  const int* __restrict__ dst,
                                                  int* __restrict__ cursor,
                                                  int* __restrict__ esrc, int E) {
    int i = blockIdx.x * blockDim.x + threadIdx.x;
    if (i < E) {
        int p = atomicAdd(&cursor[dst[i]], 1);
        esrc[p] = src[i];
    }
}

// ---------------- MFMA GEMM + fused attn-coefficient epilogue --------------
template <int K, bool SRC32>
__global__ __launch_bounds__(256) void gemm_mfma(
    const void* __restrict__ Xv, const unsigned short* __restrict__ Wt,
    const float* __restrict__ al, const float* __restrict__ ar,
    unsigned int* __restrict__ Zg, float2* __restrict__ el2,
    float2* __restrict__ er2, int N) {
    constexpr int LDX = K + 8;
    __shared__ unsigned short Ws[128 * LDX];
    __shared__ unsigned short Xs[64 * LDX];
    const int tid = threadIdx.x;
    const int row0 = blockIdx.x * 64;

    constexpr int KC = K / 8;
    for (int i = tid; i < 128 * KC; i += 256) {
        int r = i / KC, c8 = i % KC;
        ushort8 v = *(const ushort8*)&Wt[r * K + c8 * 8];
        *(ushort8*)&Ws[r * LDX + c8 * 8] = v;
    }
    for (int i = tid; i < 64 * KC; i += 256) {
        int r = i / KC, c8 = i % KC;
        int gr = row0 + r;
        int sr = (gr < N) ? gr : 0;
        if constexpr (SRC32) {
            const float4* fp = (const float4*)((const float*)Xv + (size_t)sr * K + c8 * 8);
            float4 v0 = fp[0], v1 = fp[1];
            ushort8 o = {(unsigned short)f2bf(v0.x), (unsigned short)f2bf(v0.y),
                         (unsigned short)f2bf(v0.z), (unsigned short)f2bf(v0.w),
                         (unsigned short)f2bf(v1.x), (unsigned short)f2bf(v1.y),
                         (unsigned short)f2bf(v1.z), (unsigned short)f2bf(v1.w)};
            *(ushort8*)&Xs[r * LDX + c8 * 8] = o;
        } else {
            ushort8 v = *(const ushort8*)((const unsigned short*)Xv + (size_t)sr * K + c8 * 8);
            *(ushort8*)&Xs[r * LDX + c8 * 8] = v;
        }
    }
    __syncthreads();

    const int wv = tid >> 6, lane = tid & 63;
    const int m = lane & 15, q = lane >> 4;

    f32x4 acc[8];
#pragma unroll
    for (int t = 0; t < 8; ++t) {
        acc[t][0] = 0.f; acc[t][1] = 0.f; acc[t][2] = 0.f; acc[t][3] = 0.f;
    }

    const int arow = wv * 16 + m;
#pragma unroll
    for (int k0 = 0; k0 < K; k0 += 32) {
        short8 a = *(const short8*)&Xs[arow * LDX + k0 + q * 8];
#pragma unroll
        for (int t = 0; t < 8; ++t) {
            short8 b = *(const short8*)&Ws[(t * 16 + m) * LDX + k0 + q * 8];
            acc[t] = __builtin_amdgcn_mfma_f32_16x16x32_bf16(a, b, acc[t], 0, 0, 0);
        }
    }

    const int rbase = row0 + wv * 16 + q * 4;
#pragma unroll
    for (int t = 0; t < 4; ++t) {
#pragma unroll
        for (int r = 0; r < 4; ++r) {
            int gr = rbase + r;
            if (gr < N) {
                unsigned int z0 = f2bf(acc[t][r]);
                unsigned int z1 = f2bf(acc[t + 4][r]);
                Zg[(size_t)gr * 64 + t * 16 + m] = z0 | (z1 << 16);
            }
        }
    }

    float alv[8], arv[8];
#pragma unroll
    for (int t = 0; t < 8; ++t) {
        alv[t] = al[t * 16 + m];
        arv[t] = ar[t * 16 + m];
    }
#pragma unroll
    for (int r = 0; r < 4; ++r) {
        float pel0 = 0.f, pel1 = 0.f, per0 = 0.f, per1 = 0.f;
#pragma unroll
        for (int t = 0; t < 4; ++t) {
            pel0 += acc[t][r] * alv[t];
            per0 += acc[t][r] * arv[t];
            pel1 += acc[t + 4][r] * alv[t + 4];
            per1 += acc[t + 4][r] * arv[t + 4];
        }
#pragma unroll
        for (int off = 1; off < 16; off <<= 1) {
            pel0 += __shfl_xor(pel0, off);
            pel1 += __shfl_xor(pel1, off);
            per0 += __shfl_xor(per0, off);
            per1 += __shfl_xor(per1, off);
        }
        int gr = rbase + r;
        if (m == 0 && gr < N) {
            el2[gr] = make_float2(pel0, pel1);
            er2[gr] = make_float2(per0, per1);
        }
    }
}

// ---------------- aggregate: group-per-node, inline softmax weights --------
// 16 nodes/block; 16-lane group per node. Strip-load esrc (coalesced dword),
// gather el2[sv] (L2-hot, off the Zg address chain), exp inline, then
// 4x-unrolled dwordx4 row gathers with zero-weight padding to mult-of-4.
__global__ __launch_bounds__(256) void aggregate(
    const uint4* __restrict__ Zg4, const int* __restrict__ esrc,
    const float2* __restrict__ el2, const float2* __restrict__ er2,
    const int* __restrict__ row_start, const float* __restrict__ bias,
    const float* __restrict__ gamma, const float* __restrict__ beta,
    unsigned short* __restrict__ out_bf, float* __restrict__ out_f,
    int N, int do_ln) {
    const int tid = threadIdx.x;
    const int li = tid & 15;
    const int gb = tid & 48;           // group base lane within wave
    const int node = blockIdx.x * 16 + (tid >> 4);
    const bool valid = node < N;
    const int s0 = valid ? row_start[node] : 0;
    const int s1 = valid ? row_start[node + 1] : 0;
    const float2 er = valid ? er2[node] : make_float2(0.f, 0.f);

    f32x2 acc[4] = {{0.f, 0.f}, {0.f, 0.f}, {0.f, 0.f}, {0.f, 0.f}};
    float dsum0 = 0.f, dsum1 = 0.f;

    for (int base = s0; base < s1; base += 16) {
        int idx = base + li;
        int sv = 0;
        float w0 = 0.f, w1 = 0.f;
        if (idx < s1) {
            sv = esrc[idx];
            float2 elv = el2[sv];
            float e0 = elv.x + er.x;
            e0 = e0 > 0.f ? e0 : 0.2f * e0;
            float e1 = elv.y + er.y;
            e1 = e1 > 0.f ? e1 : 0.2f * e1;
            w0 = __expf(e0);
            w1 = __expf(e1);
        }
        dsum0 += w0;
        dsum1 += w1;
        const int mm4 = (min(16, s1 - base) + 3) & ~3;  // pad: w==0, sv==0 rows
        for (int e = 0; e < mm4; e += 4) {
            int sa = __shfl(sv, gb | e);
            int sb = __shfl(sv, gb | (e + 1));
            int sc = __shfl(sv, gb | (e + 2));
            int sd = __shfl(sv, gb | (e + 3));
            uint4 ua = Zg4[((size_t)(unsigned)sa << 4) + li];
            uint4 ub = Zg4[((size_t)(unsigned)sb << 4) + li];
            uint4 uc = Zg4[((size_t)(unsigned)sc << 4) + li];
            uint4 ud = Zg4[((size_t)(unsigned)sd << 4) + li];
            f32x2 wa = {__shfl(w0, gb | e), __shfl(w1, gb | e)};
            f32x2 wb = {__shfl(w0, gb | (e + 1)), __shfl(w1, gb | (e + 1))};
            f32x2 wc = {__shfl(w0, gb | (e + 2)), __shfl(w1, gb | (e + 2))};
            f32x2 wd = {__shfl(w0, gb | (e + 3)), __shfl(w1, gb | (e + 3))};
            acc[0] += wa * f32x2{bflo(ua.x), bfhi(ua.x)};
            acc[1] += wa * f32x2{bflo(ua.y), bfhi(ua.y)};
            acc[2] += wa * f32x2{bflo(ua.z), bfhi(ua.z)};
            acc[3] += wa * f32x2{bflo(ua.w), bfhi(ua.w)};
            acc[0] += wb * f32x2{bflo(ub.x), bfhi(ub.x)};
            acc[1] += wb * f32x2{bflo(ub.y), bfhi(ub.y)};
            acc[2] += wb * f32x2{bflo(ub.z), bfhi(ub.z)};
            acc[3] += wb * f32x2{bflo(ub.w), bfhi(ub.w)};
            acc[0] += wc * f32x2{bflo(uc.x), bfhi(uc.x)};
            acc[1] += wc * f32x2{bflo(uc.y), bfhi(uc.y)};
            acc[2] += wc * f32x2{bflo(uc.z), bfhi(uc.z)};
            acc[3] += wc * f32x2{bflo(uc.w), bfhi(uc.w)};
            acc[0] += wd * f32x2{bflo(ud.x), bfhi(ud.x)};
            acc[1] += wd * f32x2{bflo(ud.y), bfhi(ud.y)};
            acc[2] += wd * f32x2{bflo(ud.z), bfhi(ud.z)};
            acc[3] += wd * f32x2{bflo(ud.w), bfhi(ud.w)};
        }
    }

    // group-local reductions (16-lane butterflies)
#pragma unroll
    for (int off = 1; off < 16; off <<= 1) {
        dsum0 += __shfl_xor(dsum0, off);
        dsum1 += __shfl_xor(dsum1, off);
    }
    float inv0 = dsum0 > 0.f ? 1.f / dsum0 : 0.f;
    float inv1 = dsum1 > 0.f ? 1.f / dsum1 : 0.f;

    if (!valid) return;

    float4 blo = *(const float4*)&bias[li * 4];
    float4 bhi = *(const float4*)&bias[64 + li * 4];
    float m0[4];
    m0[0] = (acc[0][0] * inv0 + acc[0][1] * inv1) * 0.5f + 0.5f * (blo.x + bhi.x);
    m0[1] = (acc[1][0] * inv0 + acc[1][1] * inv1) * 0.5f + 0.5f * (blo.y + bhi.y);
    m0[2] = (acc[2][0] * inv0 + acc[2][1] * inv1) * 0.5f + 0.5f * (blo.z + bhi.z);
    m0[3] = (acc[3][0] * inv0 + acc[3][1] * inv1) * 0.5f + 0.5f * (blo.w + bhi.w);

    if (do_ln) {
        float s = m0[0] + m0[1] + m0[2] + m0[3];
#pragma unroll
        for (int off = 1; off < 16; off <<= 1) s += __shfl_xor(s, off);
        float mu = s * (1.f / 64.f);
        float d0 = m0[0] - mu, d1 = m0[1] - mu, d2 = m0[2] - mu, d3 = m0[3] - mu;
        float v = d0 * d0 + d1 * d1 + d2 * d2 + d3 * d3;
#pragma unroll
        for (int off = 1; off < 16; off <<= 1) v += __shfl_xor(v, off);
        float rstd = rsqrtf(v * (1.f / 64.f) + 1e-5f);
        float4 g4 = *(const float4*)&gamma[li * 4];
        float4 be4 = *(const float4*)&beta[li * 4];
        float y0 = d0 * rstd * g4.x + be4.x;
        float y1 = d1 * rstd * g4.y + be4.y;
        float y2 = d2 * rstd * g4.z + be4.z;
        float y3 = d3 * rstd * g4.w + be4.w;
        y0 = y0 > 0.f ? y0 : 0.f;
        y1 = y1 > 0.f ? y1 : 0.f;
        y2 = y2 > 0.f ? y2 : 0.f;
        y3 = y3 > 0.f ? y3 : 0.f;
        ushort4 o = {(unsigned short)f2bf(y0), (unsigned short)f2bf(y1),
                     (unsigned short)f2bf(y2), (unsigned short)f2bf(y3)};
        *(ushort4*)&out_bf[(size_t)node * 64 + li * 4] = o;
    } else {
        *(float4*)&out_f[(size_t)node * 64 + li * 4] =
            make_float4(m0[0], m0[1], m0[2], m0[3]);
    }
}

// ---------------------------------------------------------------------------
static inline char* align_up(char* p, size_t a) {
    return (char*)(((uintptr_t)p + a - 1) & ~(uintptr_t)(a - 1));
}

extern "C" void kernel_launch(void* const* d_in, const int* in_sizes, int n_in,
                              void* d_out, int out_size, void* d_ws, size_t ws_size,
                              hipStream_t stream) {
    const float* feat = (const float*)d_in[0];
    const int* src = (const int*)d_in[1];
    const int* dst = (const int*)d_in[2];
    const float* W1 = (const float*)d_in[3];
    const float* al1 = (const float*)d_in[4];
    const float* ar1 = (const float*)d_in[5];
    const float* b1 = (const float*)d_in[6];
    const float* gamma1 = (const float*)d_in[7];
    const float* beta1 = (const float*)d_in[8];
    const float* W2 = (const float*)d_in[9];
    const float* al2 = (const float*)d_in[10];
    const float* ar2 = (const float*)d_in[11];
    const float* b2 = (const float*)d_in[12];

    const int N = in_sizes[0] / 128;
    const int E = in_sizes[1];

    char* p = (char*)d_ws;
    p = align_up(p, 256);
    unsigned int* Zg = (unsigned int*)p;            p += (size_t)N * 64 * 4;
    float2* el2 = (float2*)p;                       p += (size_t)N * 8;
    float2* er2 = (float2*)p;                       p += (size_t)N * 8;
    int* counts = (int*)p;                          p += (size_t)N * 4;
    int* row_start = (int*)p;                       p += (size_t)(N + 1) * 4;
    int* cursor = (int*)p;                          p += (size_t)N * 4;
    int* bsum = (int*)p;                            p += 1024 * 4;
    int* esrc = (int*)p;                            p += (size_t)E * 4;
    p = align_up(p, 64);
    unsigned short* hb = (unsigned short*)p;        p += (size_t)N * 64 * 2;
    p = align_up(p, 64);
    unsigned short* W1t = (unsigned short*)p;       p += 128 * 128 * 2;
    unsigned short* W2t = (unsigned short*)p;       p += 128 * 64 * 2;

    const int nb = (N + 1023) / 1024;
    const int init_work = 128 * 128 + 64 * 128 + N;

    init_small<<<(init_work + 255) / 256, 256, 0, stream>>>(W1, W1t, W2, W2t, counts, N);
    count_deg<<<(E + 255) / 256, 256, 0, stream>>>(dst, counts, E);
    scan1<<<nb, 1024, 0, stream>>>(counts, row_start, bsum, N);
    scan2<<<1, 1024, 0, stream>>>(bsum, nb);
    scan3<<<nb, 1024, 0, stream>>>(row_start, bsum, cursor, N, E);
    fill_edges<<<(E + 255) / 256, 256, 0, stream>>>(src, dst, cursor, esrc, E);

    // layer 0
    gemm_mfma<128, true><<<(N + 63) / 64, 256, 0, stream>>>(feat, W1t, al1, ar1,
                                                            Zg, el2, er2, N);
    aggregate<<<(N + 15) / 16, 256, 0, stream>>>((const uint4*)Zg, esrc, el2, er2,
                                                 row_start, b1, gamma1, beta1,
                                                 hb, nullptr, N, 1);

    // layer 1
    gemm_mfma<64, false><<<(N + 63) / 64, 256, 0, stream>>>(hb, W2t, al2, ar2,
                                                            Zg, el2, er2, N);
    aggregate<<<(N + 15) / 16, 256, 0, stream>>>((const uint4*)Zg, esrc, el2, er2,
                                                 row_start, b2, nullptr, nullptr,
                                                 nullptr, (float*)d_out, N, 0);
}

// Round 7
// 239.847 us; speedup vs baseline: 1.3981x; 1.2568x over previous
//
#include <hip/hip_runtime.h>

// ---------------------------------------------------------------------------
// 2-layer GAT (H=2, D=64, Fin=128) on MI355X.
// bf16 MFMA GEMMs (fused attn-coeff epilogue), packed-bf16 Z rows,
// BINNED CSR build (bucket = 256 dst nodes; staging append + in-bucket
// scatter for line-dense writes), aggregation with 16-lane groups / 4 nodes
// per wave, inline softmax weights, 4x-unrolled dwordx4 row gathers.
// ---------------------------------------------------------------------------

typedef __attribute__((ext_vector_type(8))) short short8;
typedef __attribute__((ext_vector_type(8))) unsigned short ushort8;
typedef __attribute__((ext_vector_type(4))) float f32x4;
typedef __attribute__((ext_vector_type(2))) float f32x2;

#define BKT_SHIFT 8            // 256 dst nodes per bucket
#define BKT_MAX 512            // >= ceil(100000/256)=391
#define BIN_EPT 8              // edges per thread in hist/bin kernels
#define BIN_TPB 1024

__device__ inline unsigned int f2bf(float x) {
    unsigned int u = __builtin_bit_cast(unsigned int, x);
    return (u + 0x7fffu + ((u >> 16) & 1u)) >> 16;   // RNE
}
__device__ inline float bflo(unsigned int u) {
    return __builtin_bit_cast(float, u << 16);
}
__device__ inline float bfhi(unsigned int u) {
    return __builtin_bit_cast(float, u & 0xffff0000u);
}

// ---------------- init: W transposes + zero bucket counters ----------------
__global__ __launch_bounds__(256) void init_small(
    const float* __restrict__ W1, unsigned short* __restrict__ W1t,
    const float* __restrict__ W2, unsigned short* __restrict__ W2t,
    int* __restrict__ bucket_cnt) {
    int i = blockIdx.x * 256 + threadIdx.x;
    if (i < 128 * 128) {
        int k = i >> 7, c = i & 127;
        W1t[c * 128 + k] = (unsigned short)f2bf(W1[i]);
        return;
    }
    int l = i - 128 * 128;
    if (l < 64 * 128) {
        int k = l >> 7, c = l & 127;
        W2t[c * 64 + k] = (unsigned short)f2bf(W2[l]);
        return;
    }
    int q = l - 64 * 128;
    if (q < BKT_MAX) bucket_cnt[q] = 0;
}

// ---------------- binned CSR build ----------------
// Pass A: per-bucket edge histogram (LDS-aggregated).
__global__ __launch_bounds__(BIN_TPB) void hist_buckets(const int* __restrict__ dst,
                                                        int* __restrict__ bucket_cnt,
                                                        int E) {
    __shared__ int cnt[BKT_MAX];
    const int tid = threadIdx.x;
    for (int j = tid; j < BKT_MAX; j += BIN_TPB) cnt[j] = 0;
    __syncthreads();
    const int base = blockIdx.x * (BIN_TPB * BIN_EPT);
#pragma unroll
    for (int k = 0; k < BIN_EPT; ++k) {
        int idx = base + k * BIN_TPB + tid;
        if (idx < E) atomicAdd(&cnt[dst[idx] >> BKT_SHIFT], 1);
    }
    __syncthreads();
    for (int j = tid; j < BKT_MAX; j += BIN_TPB)
        if (cnt[j]) atomicAdd(&bucket_cnt[j], cnt[j]);
}

// Pass B: exclusive scan over buckets; init cursors; row_start[N]=E.
__global__ __launch_bounds__(BKT_MAX) void scan_buckets(const int* __restrict__ bucket_cnt,
                                                        int* __restrict__ bucket_start,
                                                        int* __restrict__ bucket_cursor,
                                                        int* __restrict__ row_start,
                                                        int B, int N, int E) {
    __shared__ int s[BKT_MAX];
    const int tid = threadIdx.x;
    int own = (tid < B) ? bucket_cnt[tid] : 0;
    s[tid] = own;
    __syncthreads();
    for (int off = 1; off < BKT_MAX; off <<= 1) {
        int t = (tid >= off) ? s[tid - off] : 0;
        __syncthreads();
        s[tid] += t;
        __syncthreads();
    }
    int excl = s[tid] - own;
    if (tid < B) {
        bucket_start[tid] = excl;
        bucket_cursor[tid] = excl;
        if (tid == B - 1) bucket_start[B] = s[tid];
    }
    if (tid == 0) row_start[N] = E;
}

// Pass C: append packed (local_dst<<24 | src) into bucket staging ranges.
// Per-block LDS ranks + one global atomic per (block,bucket).
__global__ __launch_bounds__(BIN_TPB) void bin_edges(const int* __restrict__ src,
                                                     const int* __restrict__ dst,
                                                     int* __restrict__ bucket_cursor,
                                                     unsigned int* __restrict__ staging,
                                                     int E) {
    __shared__ int lcnt[BKT_MAX];
    __shared__ int lbase[BKT_MAX];
    const int tid = threadIdx.x;
    for (int j = tid; j < BKT_MAX; j += BIN_TPB) lcnt[j] = 0;
    __syncthreads();
    const int base = blockIdx.x * (BIN_TPB * BIN_EPT);
    int b[BIN_EPT], rank[BIN_EPT];
    unsigned int pay[BIN_EPT];
#pragma unroll
    for (int k = 0; k < BIN_EPT; ++k) {
        int idx = base + k * BIN_TPB + tid;
        b[k] = -1;
        if (idx < E) {
            int d = dst[idx];
            b[k] = d >> BKT_SHIFT;
            pay[k] = ((unsigned)(d & ((1 << BKT_SHIFT) - 1)) << 24) | (unsigned)src[idx];
            rank[k] = atomicAdd(&lcnt[b[k]], 1);
        }
    }
    __syncthreads();
    for (int j = tid; j < BKT_MAX; j += BIN_TPB)
        if (lcnt[j]) lbase[j] = atomicAdd(&bucket_cursor[j], lcnt[j]);
    __syncthreads();
#pragma unroll
    for (int k = 0; k < BIN_EPT; ++k)
        if (b[k] >= 0) staging[lbase[b[k]] + rank[k]] = pay[k];
}

// Pass D: one block per bucket: per-node hist -> scan -> row_start (coalesced)
// -> scatter esrc into the bucket's contiguous CSR range (line-dense).
__global__ __launch_bounds__(256) void build_csr(const unsigned int* __restrict__ staging,
                                                 const int* __restrict__ bucket_start,
                                                 int* __restrict__ row_start,
                                                 int* __restrict__ esrc, int N) {
    __shared__ int hist[256];
    __shared__ int cur[256];
    const int tid = threadIdx.x;
    const int bkt = blockIdx.x;
    const int node0 = bkt << BKT_SHIFT;
    const int ebase = bucket_start[bkt];
    const int ecount = bucket_start[bkt + 1] - ebase;

    hist[tid] = 0;
    __syncthreads();
    for (int e = tid; e < ecount; e += 256)
        atomicAdd(&hist[staging[ebase + e] >> 24], 1);
    __syncthreads();
    int own = hist[tid];
    // inclusive scan over 256 entries
    for (int off = 1; off < 256; off <<= 1) {
        int t = (tid >= off) ? hist[tid - off] : 0;
        __syncthreads();
        hist[tid] += t;
        __syncthreads();
    }
    int excl = hist[tid] - own;
    if (node0 + tid < N) row_start[node0 + tid] = ebase + excl;
    cur[tid] = ebase + excl;
    __syncthreads();
    for (int e = tid; e < ecount; e += 256) {
        unsigned int p = staging[ebase + e];
        int slot = atomicAdd(&cur[p >> 24], 1);
        esrc[slot] = (int)(p & 0xFFFFFFu);
    }
}

// ---------------- MFMA GEMM + fused attn-coefficient epilogue --------------
template <int K, bool SRC32>
__global__ __launch_bounds__(256) void gemm_mfma(
    const void* __restrict__ Xv, const unsigned short* __restrict__ Wt,
    const float* __restrict__ al, const float* __restrict__ ar,
    unsigned int* __restrict__ Zg, float2* __restrict__ el2,
    float2* __restrict__ er2, int N) {
    constexpr int LDX = K + 8;
    __shared__ unsigned short Ws[128 * LDX];
    __shared__ unsigned short Xs[64 * LDX];
    const int tid = threadIdx.x;
    const int row0 = blockIdx.x * 64;

    constexpr int KC = K / 8;
    for (int i = tid; i < 128 * KC; i += 256) {
        int r = i / KC, c8 = i % KC;
        ushort8 v = *(const ushort8*)&Wt[r * K + c8 * 8];
        *(ushort8*)&Ws[r * LDX + c8 * 8] = v;
    }
    for (int i = tid; i < 64 * KC; i += 256) {
        int r = i / KC, c8 = i % KC;
        int gr = row0 + r;
        int sr = (gr < N) ? gr : 0;
        if constexpr (SRC32) {
            const float4* fp = (const float4*)((const float*)Xv + (size_t)sr * K + c8 * 8);
            float4 v0 = fp[0], v1 = fp[1];
            ushort8 o = {(unsigned short)f2bf(v0.x), (unsigned short)f2bf(v0.y),
                         (unsigned short)f2bf(v0.z), (unsigned short)f2bf(v0.w),
                         (unsigned short)f2bf(v1.x), (unsigned short)f2bf(v1.y),
                         (unsigned short)f2bf(v1.z), (unsigned short)f2bf(v1.w)};
            *(ushort8*)&Xs[r * LDX + c8 * 8] = o;
        } else {
            ushort8 v = *(const ushort8*)((const unsigned short*)Xv + (size_t)sr * K + c8 * 8);
            *(ushort8*)&Xs[r * LDX + c8 * 8] = v;
        }
    }
    __syncthreads();

    const int wv = tid >> 6, lane = tid & 63;
    const int m = lane & 15, q = lane >> 4;

    f32x4 acc[8];
#pragma unroll
    for (int t = 0; t < 8; ++t) {
        acc[t][0] = 0.f; acc[t][1] = 0.f; acc[t][2] = 0.f; acc[t][3] = 0.f;
    }

    const int arow = wv * 16 + m;
#pragma unroll
    for (int k0 = 0; k0 < K; k0 += 32) {
        short8 a = *(const short8*)&Xs[arow * LDX + k0 + q * 8];
#pragma unroll
        for (int t = 0; t < 8; ++t) {
            short8 b = *(const short8*)&Ws[(t * 16 + m) * LDX + k0 + q * 8];
            acc[t] = __builtin_amdgcn_mfma_f32_16x16x32_bf16(a, b, acc[t], 0, 0, 0);
        }
    }

    const int rbase = row0 + wv * 16 + q * 4;
#pragma unroll
    for (int t = 0; t < 4; ++t) {
#pragma unroll
        for (int r = 0; r < 4; ++r) {
            int gr = rbase + r;
            if (gr < N) {
                unsigned int z0 = f2bf(acc[t][r]);
                unsigned int z1 = f2bf(acc[t + 4][r]);
                Zg[(size_t)gr * 64 + t * 16 + m] = z0 | (z1 << 16);
            }
        }
    }

    float alv[8], arv[8];
#pragma unroll
    for (int t = 0; t < 8; ++t) {
        alv[t] = al[t * 16 + m];
        arv[t] = ar[t * 16 + m];
    }
#pragma unroll
    for (int r = 0; r < 4; ++r) {
        float pel0 = 0.f, pel1 = 0.f, per0 = 0.f, per1 = 0.f;
#pragma unroll
        for (int t = 0; t < 4; ++t) {
            pel0 += acc[t][r] * alv[t];
            per0 += acc[t][r] * arv[t];
            pel1 += acc[t + 4][r] * alv[t + 4];
            per1 += acc[t + 4][r] * arv[t + 4];
        }
#pragma unroll
        for (int off = 1; off < 16; off <<= 1) {
            pel0 += __shfl_xor(pel0, off);
            pel1 += __shfl_xor(pel1, off);
            per0 += __shfl_xor(per0, off);
            per1 += __shfl_xor(per1, off);
        }
        int gr = rbase + r;
        if (m == 0 && gr < N) {
            el2[gr] = make_float2(pel0, pel1);
            er2[gr] = make_float2(per0, per1);
        }
    }
}

// ---------------- aggregate: group-per-node, inline softmax weights --------
__global__ __launch_bounds__(256) void aggregate(
    const uint4* __restrict__ Zg4, const int* __restrict__ esrc,
    const float2* __restrict__ el2, const float2* __restrict__ er2,
    const int* __restrict__ row_start, const float* __restrict__ bias,
    const float* __restrict__ gamma, const float* __restrict__ beta,
    unsigned short* __restrict__ out_bf, float* __restrict__ out_f,
    int N, int do_ln) {
    const int tid = threadIdx.x;
    const int li = tid & 15;
    const int gb = tid & 48;
    const int node = blockIdx.x * 16 + (tid >> 4);
    const bool valid = node < N;
    const int s0 = valid ? row_start[node] : 0;
    const int s1 = valid ? row_start[node + 1] : 0;
    const float2 er = valid ? er2[node] : make_float2(0.f, 0.f);

    f32x2 acc[4] = {{0.f, 0.f}, {0.f, 0.f}, {0.f, 0.f}, {0.f, 0.f}};
    float dsum0 = 0.f, dsum1 = 0.f;

    for (int base = s0; base < s1; base += 16) {
        int idx = base + li;
        int sv = 0;
        float w0 = 0.f, w1 = 0.f;
        if (idx < s1) {
            sv = esrc[idx];
            float2 elv = el2[sv];
            float e0 = elv.x + er.x;
            e0 = e0 > 0.f ? e0 : 0.2f * e0;
            float e1 = elv.y + er.y;
            e1 = e1 > 0.f ? e1 : 0.2f * e1;
            w0 = __expf(e0);
            w1 = __expf(e1);
        }
        dsum0 += w0;
        dsum1 += w1;
        const int mm4 = (min(16, s1 - base) + 3) & ~3;
        for (int e = 0; e < mm4; e += 4) {
            int sa = __shfl(sv, gb | e);
            int sb = __shfl(sv, gb | (e + 1));
            int sc = __shfl(sv, gb | (e + 2));
            int sd = __shfl(sv, gb | (e + 3));
            uint4 ua = Zg4[((size_t)(unsigned)sa << 4) + li];
            uint4 ub = Zg4[((size_t)(unsigned)sb << 4) + li];
            uint4 uc = Zg4[((size_t)(unsigned)sc << 4) + li];
            uint4 ud = Zg4[((size_t)(unsigned)sd << 4) + li];
            f32x2 wa = {__shfl(w0, gb | e), __shfl(w1, gb | e)};
            f32x2 wb = {__shfl(w0, gb | (e + 1)), __shfl(w1, gb | (e + 1))};
            f32x2 wc = {__shfl(w0, gb | (e + 2)), __shfl(w1, gb | (e + 2))};
            f32x2 wd = {__shfl(w0, gb | (e + 3)), __shfl(w1, gb | (e + 3))};
            acc[0] += wa * f32x2{bflo(ua.x), bfhi(ua.x)};
            acc[1] += wa * f32x2{bflo(ua.y), bfhi(ua.y)};
            acc[2] += wa * f32x2{bflo(ua.z), bfhi(ua.z)};
            acc[3] += wa * f32x2{bflo(ua.w), bfhi(ua.w)};
            acc[0] += wb * f32x2{bflo(ub.x), bfhi(ub.x)};
            acc[1] += wb * f32x2{bflo(ub.y), bfhi(ub.y)};
            acc[2] += wb * f32x2{bflo(ub.z), bfhi(ub.z)};
            acc[3] += wb * f32x2{bflo(ub.w), bfhi(ub.w)};
            acc[0] += wc * f32x2{bflo(uc.x), bfhi(uc.x)};
            acc[1] += wc * f32x2{bflo(uc.y), bfhi(uc.y)};
            acc[2] += wc * f32x2{bflo(uc.z), bfhi(uc.z)};
            acc[3] += wc * f32x2{bflo(uc.w), bfhi(uc.w)};
            acc[0] += wd * f32x2{bflo(ud.x), bfhi(ud.x)};
            acc[1] += wd * f32x2{bflo(ud.y), bfhi(ud.y)};
            acc[2] += wd * f32x2{bflo(ud.z), bfhi(ud.z)};
            acc[3] += wd * f32x2{bflo(ud.w), bfhi(ud.w)};
        }
    }

#pragma unroll
    for (int off = 1; off < 16; off <<= 1) {
        dsum0 += __shfl_xor(dsum0, off);
        dsum1 += __shfl_xor(dsum1, off);
    }
    float inv0 = dsum0 > 0.f ? 1.f / dsum0 : 0.f;
    float inv1 = dsum1 > 0.f ? 1.f / dsum1 : 0.f;

    if (!valid) return;

    float4 blo = *(const float4*)&bias[li * 4];
    float4 bhi = *(const float4*)&bias[64 + li * 4];
    float m0[4];
    m0[0] = (acc[0][0] * inv0 + acc[0][1] * inv1) * 0.5f + 0.5f * (blo.x + bhi.x);
    m0[1] = (acc[1][0] * inv0 + acc[1][1] * inv1) * 0.5f + 0.5f * (blo.y + bhi.y);
    m0[2] = (acc[2][0] * inv0 + acc[2][1] * inv1) * 0.5f + 0.5f * (blo.z + bhi.z);
    m0[3] = (acc[3][0] * inv0 + acc[3][1] * inv1) * 0.5f + 0.5f * (blo.w + bhi.w);

    if (do_ln) {
        float s = m0[0] + m0[1] + m0[2] + m0[3];
#pragma unroll
        for (int off = 1; off < 16; off <<= 1) s += __shfl_xor(s, off);
        float mu = s * (1.f / 64.f);
        float d0 = m0[0] - mu, d1 = m0[1] - mu, d2 = m0[2] - mu, d3 = m0[3] - mu;
        float v = d0 * d0 + d1 * d1 + d2 * d2 + d3 * d3;
#pragma unroll
        for (int off = 1; off < 16; off <<= 1) v += __shfl_xor(v, off);
        float rstd = rsqrtf(v * (1.f / 64.f) + 1e-5f);
        float4 g4 = *(const float4*)&gamma[li * 4];
        float4 be4 = *(const float4*)&beta[li * 4];
        float y0 = d0 * rstd * g4.x + be4.x;
        float y1 = d1 * rstd * g4.y + be4.y;
        float y2 = d2 * rstd * g4.z + be4.z;
        float y3 = d3 * rstd * g4.w + be4.w;
        y0 = y0 > 0.f ? y0 : 0.f;
        y1 = y1 > 0.f ? y1 : 0.f;
        y2 = y2 > 0.f ? y2 : 0.f;
        y3 = y3 > 0.f ? y3 : 0.f;
        ushort4 o = {(unsigned short)f2bf(y0), (unsigned short)f2bf(y1),
                     (unsigned short)f2bf(y2), (unsigned short)f2bf(y3)};
        *(ushort4*)&out_bf[(size_t)node * 64 + li * 4] = o;
    } else {
        *(float4*)&out_f[(size_t)node * 64 + li * 4] =
            make_float4(m0[0], m0[1], m0[2], m0[3]);
    }
}

// ---------------------------------------------------------------------------
static inline char* align_up(char* p, size_t a) {
    return (char*)(((uintptr_t)p + a - 1) & ~(uintptr_t)(a - 1));
}

extern "C" void kernel_launch(void* const* d_in, const int* in_sizes, int n_in,
                              void* d_out, int out_size, void* d_ws, size_t ws_size,
                              hipStream_t stream) {
    const float* feat = (const float*)d_in[0];
    const int* src = (const int*)d_in[1];
    const int* dst = (const int*)d_in[2];
    const float* W1 = (const float*)d_in[3];
    const float* al1 = (const float*)d_in[4];
    const float* ar1 = (const float*)d_in[5];
    const float* b1 = (const float*)d_in[6];
    const float* gamma1 = (const float*)d_in[7];
    const float* beta1 = (const float*)d_in[8];
    const float* W2 = (const float*)d_in[9];
    const float* al2 = (const float*)d_in[10];
    const float* ar2 = (const float*)d_in[11];
    const float* b2 = (const float*)d_in[12];

    const int N = in_sizes[0] / 128;
    const int E = in_sizes[1];
    const int B = (N + (1 << BKT_SHIFT) - 1) >> BKT_SHIFT;   // buckets

    char* p = (char*)d_ws;
    p = align_up(p, 256);
    unsigned int* Zg = (unsigned int*)p;            p += (size_t)N * 64 * 4;
    float2* el2 = (float2*)p;                       p += (size_t)N * 8;
    float2* er2 = (float2*)p;                       p += (size_t)N * 8;
    int* row_start = (int*)p;                       p += (size_t)(N + 1) * 4;
    int* bucket_cnt = (int*)p;                      p += BKT_MAX * 4;
    int* bucket_start = (int*)p;                    p += (BKT_MAX + 1) * 4;
    int* bucket_cursor = (int*)p;                   p += BKT_MAX * 4;
    unsigned int* staging = (unsigned int*)p;       p += (size_t)E * 4;
    int* esrc = (int*)p;                            p += (size_t)E * 4;
    p = align_up(p, 64);
    unsigned short* hb = (unsigned short*)p;        p += (size_t)N * 64 * 2;
    p = align_up(p, 64);
    unsigned short* W1t = (unsigned short*)p;       p += 128 * 128 * 2;
    unsigned short* W2t = (unsigned short*)p;       p += 128 * 64 * 2;

    const int init_work = 128 * 128 + 64 * 128 + BKT_MAX;
    const int bin_blocks = (E + BIN_TPB * BIN_EPT - 1) / (BIN_TPB * BIN_EPT);

    init_small<<<(init_work + 255) / 256, 256, 0, stream>>>(W1, W1t, W2, W2t, bucket_cnt);
    hist_buckets<<<bin_blocks, BIN_TPB, 0, stream>>>(dst, bucket_cnt, E);
    scan_buckets<<<1, BKT_MAX, 0, stream>>>(bucket_cnt, bucket_start, bucket_cursor,
                                            row_start, B, N, E);
    bin_edges<<<bin_blocks, BIN_TPB, 0, stream>>>(src, dst, bucket_cursor, staging, E);
    build_csr<<<B, 256, 0, stream>>>(staging, bucket_start, row_start, esrc, N);

    // layer 0
    gemm_mfma<128, true><<<(N + 63) / 64, 256, 0, stream>>>(feat, W1t, al1, ar1,
                                                            Zg, el2, er2, N);
    aggregate<<<(N + 15) / 16, 256, 0, stream>>>((const uint4*)Zg, esrc, el2, er2,
                                                 row_start, b1, gamma1, beta1,
                                                 hb, nullptr, N, 1);

    // layer 1
    gemm_mfma<64, false><<<(N + 63) / 64, 256, 0, stream>>>(hb, W2t, al2, ar2,
                                                            Zg, el2, er2, N);
    aggregate<<<(N + 15) / 16, 256, 0, stream>>>((const uint4*)Zg, esrc, el2, er2,
                                                 row_start, b2, nullptr, nullptr,
                                                 nullptr, (float*)d_out, N, 0);
}

// Round 8
// 238.650 us; speedup vs baseline: 1.4051x; 1.0050x over previous
//
#include <hip/hip_runtime.h>

// ---------------------------------------------------------------------------
// 2-layer GAT (H=2, D=64, Fin=128) on MI355X.
// bf16 MFMA GEMMs (fused attn-coeff epilogue), packed-bf16 Z rows,
// BINNED CSR build (bucket = 256 dst nodes), aggregation with 16-lane
// groups / 4 nodes per wave, inline softmax weights packed to bf16 pairs,
// v_dot2_f32_bf16 inner loop (no unpack), 4x-unrolled dwordx4 row gathers.
// ---------------------------------------------------------------------------

typedef __attribute__((ext_vector_type(8))) short short8;
typedef __attribute__((ext_vector_type(8))) unsigned short ushort8;
typedef __attribute__((ext_vector_type(4))) float f32x4;
typedef __attribute__((ext_vector_type(2))) short s16x2;

#define BKT_SHIFT 8            // 256 dst nodes per bucket
#define BKT_MAX 512            // >= ceil(100000/256)=391
#define BIN_EPT 8              // edges per thread in hist/bin kernels
#define BIN_TPB 1024

#if defined(__has_builtin)
#if __has_builtin(__builtin_amdgcn_fdot2_f32_bf16)
#define HAS_BF16_DOT2 1
#endif
#endif

__device__ inline unsigned int f2bf(float x) {
    unsigned int u = __builtin_bit_cast(unsigned int, x);
    return (u + 0x7fffu + ((u >> 16) & 1u)) >> 16;   // RNE
}
__device__ inline float bflo(unsigned int u) {
    return __builtin_bit_cast(float, u << 16);
}
__device__ inline float bfhi(unsigned int u) {
    return __builtin_bit_cast(float, u & 0xffff0000u);
}
#ifdef HAS_BF16_DOT2
__device__ inline float dot2bf(unsigned int zpair, unsigned int wpair, float acc) {
    return __builtin_amdgcn_fdot2_f32_bf16(__builtin_bit_cast(s16x2, zpair),
                                           __builtin_bit_cast(s16x2, wpair),
                                           acc, false);
}
#endif

// ---------------- init: W transposes + zero bucket counters ----------------
__global__ __launch_bounds__(256) void init_small(
    const float* __restrict__ W1, unsigned short* __restrict__ W1t,
    const float* __restrict__ W2, unsigned short* __restrict__ W2t,
    int* __restrict__ bucket_cnt) {
    int i = blockIdx.x * 256 + threadIdx.x;
    if (i < 128 * 128) {
        int k = i >> 7, c = i & 127;
        W1t[c * 128 + k] = (unsigned short)f2bf(W1[i]);
        return;
    }
    int l = i - 128 * 128;
    if (l < 64 * 128) {
        int k = l >> 7, c = l & 127;
        W2t[c * 64 + k] = (unsigned short)f2bf(W2[l]);
        return;
    }
    int q = l - 64 * 128;
    if (q < BKT_MAX) bucket_cnt[q] = 0;
}

// ---------------- binned CSR build ----------------
__global__ __launch_bounds__(BIN_TPB) void hist_buckets(const int* __restrict__ dst,
                                                        int* __restrict__ bucket_cnt,
                                                        int E) {
    __shared__ int cnt[BKT_MAX];
    const int tid = threadIdx.x;
    for (int j = tid; j < BKT_MAX; j += BIN_TPB) cnt[j] = 0;
    __syncthreads();
    const int base = blockIdx.x * (BIN_TPB * BIN_EPT);
#pragma unroll
    for (int k = 0; k < BIN_EPT; ++k) {
        int idx = base + k * BIN_TPB + tid;
        if (idx < E) atomicAdd(&cnt[dst[idx] >> BKT_SHIFT], 1);
    }
    __syncthreads();
    for (int j = tid; j < BKT_MAX; j += BIN_TPB)
        if (cnt[j]) atomicAdd(&bucket_cnt[j], cnt[j]);
}

__global__ __launch_bounds__(BKT_MAX) void scan_buckets(const int* __restrict__ bucket_cnt,
                                                        int* __restrict__ bucket_start,
                                                        int* __restrict__ bucket_cursor,
                                                        int* __restrict__ row_start,
                                                        int B, int N, int E) {
    __shared__ int s[BKT_MAX];
    const int tid = threadIdx.x;
    int own = (tid < B) ? bucket_cnt[tid] : 0;
    s[tid] = own;
    __syncthreads();
    for (int off = 1; off < BKT_MAX; off <<= 1) {
        int t = (tid >= off) ? s[tid - off] : 0;
        __syncthreads();
        s[tid] += t;
        __syncthreads();
    }
    int excl = s[tid] - own;
    if (tid < B) {
        bucket_start[tid] = excl;
        bucket_cursor[tid] = excl;
        if (tid == B - 1) bucket_start[B] = s[tid];
    }
    if (tid == 0) row_start[N] = E;
}

__global__ __launch_bounds__(BIN_TPB) void bin_edges(const int* __restrict__ src,
                                                     const int* __restrict__ dst,
                                                     int* __restrict__ bucket_cursor,
                                                     unsigned int* __restrict__ staging,
                                                     int E) {
    __shared__ int lcnt[BKT_MAX];
    __shared__ int lbase[BKT_MAX];
    const int tid = threadIdx.x;
    for (int j = tid; j < BKT_MAX; j += BIN_TPB) lcnt[j] = 0;
    __syncthreads();
    const int base = blockIdx.x * (BIN_TPB * BIN_EPT);
    int b[BIN_EPT], rank[BIN_EPT];
    unsigned int pay[BIN_EPT];
#pragma unroll
    for (int k = 0; k < BIN_EPT; ++k) {
        int idx = base + k * BIN_TPB + tid;
        b[k] = -1;
        if (idx < E) {
            int d = dst[idx];
            b[k] = d >> BKT_SHIFT;
            pay[k] = ((unsigned)(d & ((1 << BKT_SHIFT) - 1)) << 24) | (unsigned)src[idx];
            rank[k] = atomicAdd(&lcnt[b[k]], 1);
        }
    }
    __syncthreads();
    for (int j = tid; j < BKT_MAX; j += BIN_TPB)
        if (lcnt[j]) lbase[j] = atomicAdd(&bucket_cursor[j], lcnt[j]);
    __syncthreads();
#pragma unroll
    for (int k = 0; k < BIN_EPT; ++k)
        if (b[k] >= 0) staging[lbase[b[k]] + rank[k]] = pay[k];
}

__global__ __launch_bounds__(256) void build_csr(const unsigned int* __restrict__ staging,
                                                 const int* __restrict__ bucket_start,
                                                 int* __restrict__ row_start,
                                                 int* __restrict__ esrc, int N) {
    __shared__ int hist[256];
    __shared__ int cur[256];
    const int tid = threadIdx.x;
    const int bkt = blockIdx.x;
    const int node0 = bkt << BKT_SHIFT;
    const int ebase = bucket_start[bkt];
    const int ecount = bucket_start[bkt + 1] - ebase;

    hist[tid] = 0;
    __syncthreads();
    for (int e = tid; e < ecount; e += 256)
        atomicAdd(&hist[staging[ebase + e] >> 24], 1);
    __syncthreads();
    int own = hist[tid];
    for (int off = 1; off < 256; off <<= 1) {
        int t = (tid >= off) ? hist[tid - off] : 0;
        __syncthreads();
        hist[tid] += t;
        __syncthreads();
    }
    int excl = hist[tid] - own;
    if (node0 + tid < N) row_start[node0 + tid] = ebase + excl;
    cur[tid] = ebase + excl;
    __syncthreads();
    for (int e = tid; e < ecount; e += 256) {
        unsigned int p = staging[ebase + e];
        int slot = atomicAdd(&cur[p >> 24], 1);
        esrc[slot] = (int)(p & 0xFFFFFFu);
    }
}

// ---------------- MFMA GEMM + fused attn-coefficient epilogue --------------
template <int K, bool SRC32>
__global__ __launch_bounds__(256) void gemm_mfma(
    const void* __restrict__ Xv, const unsigned short* __restrict__ Wt,
    const float* __restrict__ al, const float* __restrict__ ar,
    unsigned int* __restrict__ Zg, float2* __restrict__ el2,
    float2* __restrict__ er2, int N) {
    constexpr int LDX = K + 8;
    __shared__ unsigned short Ws[128 * LDX];
    __shared__ unsigned short Xs[64 * LDX];
    const int tid = threadIdx.x;
    const int row0 = blockIdx.x * 64;

    constexpr int KC = K / 8;
    for (int i = tid; i < 128 * KC; i += 256) {
        int r = i / KC, c8 = i % KC;
        ushort8 v = *(const ushort8*)&Wt[r * K + c8 * 8];
        *(ushort8*)&Ws[r * LDX + c8 * 8] = v;
    }
    for (int i = tid; i < 64 * KC; i += 256) {
        int r = i / KC, c8 = i % KC;
        int gr = row0 + r;
        int sr = (gr < N) ? gr : 0;
        if constexpr (SRC32) {
            const float4* fp = (const float4*)((const float*)Xv + (size_t)sr * K + c8 * 8);
            float4 v0 = fp[0], v1 = fp[1];
            ushort8 o = {(unsigned short)f2bf(v0.x), (unsigned short)f2bf(v0.y),
                         (unsigned short)f2bf(v0.z), (unsigned short)f2bf(v0.w),
                         (unsigned short)f2bf(v1.x), (unsigned short)f2bf(v1.y),
                         (unsigned short)f2bf(v1.z), (unsigned short)f2bf(v1.w)};
            *(ushort8*)&Xs[r * LDX + c8 * 8] = o;
        } else {
            ushort8 v = *(const ushort8*)((const unsigned short*)Xv + (size_t)sr * K + c8 * 8);
            *(ushort8*)&Xs[r * LDX + c8 * 8] = v;
        }
    }
    __syncthreads();

    const int wv = tid >> 6, lane = tid & 63;
    const int m = lane & 15, q = lane >> 4;

    f32x4 acc[8];
#pragma unroll
    for (int t = 0; t < 8; ++t) {
        acc[t][0] = 0.f; acc[t][1] = 0.f; acc[t][2] = 0.f; acc[t][3] = 0.f;
    }

    const int arow = wv * 16 + m;
#pragma unroll
    for (int k0 = 0; k0 < K; k0 += 32) {
        short8 a = *(const short8*)&Xs[arow * LDX + k0 + q * 8];
#pragma unroll
        for (int t = 0; t < 8; ++t) {
            short8 b = *(const short8*)&Ws[(t * 16 + m) * LDX + k0 + q * 8];
            acc[t] = __builtin_amdgcn_mfma_f32_16x16x32_bf16(a, b, acc[t], 0, 0, 0);
        }
    }

    const int rbase = row0 + wv * 16 + q * 4;
#pragma unroll
    for (int t = 0; t < 4; ++t) {
#pragma unroll
        for (int r = 0; r < 4; ++r) {
            int gr = rbase + r;
            if (gr < N) {
                unsigned int z0 = f2bf(acc[t][r]);
                unsigned int z1 = f2bf(acc[t + 4][r]);
                Zg[(size_t)gr * 64 + t * 16 + m] = z0 | (z1 << 16);
            }
        }
    }

    float alv[8], arv[8];
#pragma unroll
    for (int t = 0; t < 8; ++t) {
        alv[t] = al[t * 16 + m];
        arv[t] = ar[t * 16 + m];
    }
#pragma unroll
    for (int r = 0; r < 4; ++r) {
        float pel0 = 0.f, pel1 = 0.f, per0 = 0.f, per1 = 0.f;
#pragma unroll
        for (int t = 0; t < 4; ++t) {
            pel0 += acc[t][r] * alv[t];
            per0 += acc[t][r] * arv[t];
            pel1 += acc[t + 4][r] * alv[t + 4];
            per1 += acc[t + 4][r] * arv[t + 4];
        }
#pragma unroll
        for (int off = 1; off < 16; off <<= 1) {
            pel0 += __shfl_xor(pel0, off);
            pel1 += __shfl_xor(pel1, off);
            per0 += __shfl_xor(per0, off);
            per1 += __shfl_xor(per1, off);
        }
        int gr = rbase + r;
        if (m == 0 && gr < N) {
            el2[gr] = make_float2(pel0, pel1);
            er2[gr] = make_float2(per0, per1);
        }
    }
}

// ---------------- aggregate: group-per-node, bf16-dot2 inner loop ----------
__global__ __launch_bounds__(256) void aggregate(
    const uint4* __restrict__ Zg4, const int* __restrict__ esrc,
    const float2* __restrict__ el2, const float2* __restrict__ er2,
    const int* __restrict__ row_start, const float* __restrict__ bias,
    const float* __restrict__ gamma, const float* __restrict__ beta,
    unsigned short* __restrict__ out_bf, float* __restrict__ out_f,
    int N, int do_ln) {
    const int tid = threadIdx.x;
    const int li = tid & 15;
    const int gb = tid & 48;
    const int node = blockIdx.x * 16 + (tid >> 4);
    const bool valid = node < N;
    const int s0 = valid ? row_start[node] : 0;
    const int s1 = valid ? row_start[node + 1] : 0;
    const float2 er = valid ? er2[node] : make_float2(0.f, 0.f);

    float acc0[4] = {0.f, 0.f, 0.f, 0.f};
    float acc1[4] = {0.f, 0.f, 0.f, 0.f};
    float dsum0 = 0.f, dsum1 = 0.f;

    for (int base = s0; base < s1; base += 16) {
        int idx = base + li;
        int sv = 0;
        unsigned int wpk = 0;   // bf16(w0) | bf16(w1)<<16
        if (idx < s1) {
            sv = esrc[idx];
            float2 elv = el2[sv];
            float e0 = elv.x + er.x;
            e0 = e0 > 0.f ? e0 : 0.2f * e0;
            float e1 = elv.y + er.y;
            e1 = e1 > 0.f ? e1 : 0.2f * e1;
            wpk = f2bf(__expf(e0)) | (f2bf(__expf(e1)) << 16);
        }
        // denominators from the SAME rounded weights as the numerator
        dsum0 += bflo(wpk);
        dsum1 += bfhi(wpk);
        const int mm4 = (min(16, s1 - base) + 3) & ~3;  // pad: w==0, sv==0 rows
        for (int e = 0; e < mm4; e += 4) {
            int sa = __shfl(sv, gb | e);
            int sb = __shfl(sv, gb | (e + 1));
            int sc = __shfl(sv, gb | (e + 2));
            int sd = __shfl(sv, gb | (e + 3));
            uint4 ua = Zg4[((size_t)(unsigned)sa << 4) + li];
            uint4 ub = Zg4[((size_t)(unsigned)sb << 4) + li];
            uint4 uc = Zg4[((size_t)(unsigned)sc << 4) + li];
            uint4 ud = Zg4[((size_t)(unsigned)sd << 4) + li];
            unsigned int wa = (unsigned)__shfl((int)wpk, gb | e);
            unsigned int wb = (unsigned)__shfl((int)wpk, gb | (e + 1));
            unsigned int wc = (unsigned)__shfl((int)wpk, gb | (e + 2));
            unsigned int wd = (unsigned)__shfl((int)wpk, gb | (e + 3));
#ifdef HAS_BF16_DOT2
            unsigned int wa0 = wa & 0xffffu, wa1 = wa & 0xffff0000u;
            unsigned int wb0 = wb & 0xffffu, wb1 = wb & 0xffff0000u;
            unsigned int wc0 = wc & 0xffffu, wc1 = wc & 0xffff0000u;
            unsigned int wd0 = wd & 0xffffu, wd1 = wd & 0xffff0000u;
            acc0[0] = dot2bf(ua.x, wa0, acc0[0]); acc1[0] = dot2bf(ua.x, wa1, acc1[0]);
            acc0[1] = dot2bf(ua.y, wa0, acc0[1]); acc1[1] = dot2bf(ua.y, wa1, acc1[1]);
            acc0[2] = dot2bf(ua.z, wa0, acc0[2]); acc1[2] = dot2bf(ua.z, wa1, acc1[2]);
            acc0[3] = dot2bf(ua.w, wa0, acc0[3]); acc1[3] = dot2bf(ua.w, wa1, acc1[3]);
            acc0[0] = dot2bf(ub.x, wb0, acc0[0]); acc1[0] = dot2bf(ub.x, wb1, acc1[0]);
            acc0[1] = dot2bf(ub.y, wb0, acc0[1]); acc1[1] = dot2bf(ub.y, wb1, acc1[1]);
            acc0[2] = dot2bf(ub.z, wb0, acc0[2]); acc1[2] = dot2bf(ub.z, wb1, acc1[2]);
            acc0[3] = dot2bf(ub.w, wb0, acc0[3]); acc1[3] = dot2bf(ub.w, wb1, acc1[3]);
            acc0[0] = dot2bf(uc.x, wc0, acc0[0]); acc1[0] = dot2bf(uc.x, wc1, acc1[0]);
            acc0[1] = dot2bf(uc.y, wc0, acc0[1]); acc1[1] = dot2bf(uc.y, wc1, acc1[1]);
            acc0[2] = dot2bf(uc.z, wc0, acc0[2]); acc1[2] = dot2bf(uc.z, wc1, acc1[2]);
            acc0[3] = dot2bf(uc.w, wc0, acc0[3]); acc1[3] = dot2bf(uc.w, wc1, acc1[3]);
            acc0[0] = dot2bf(ud.x, wd0, acc0[0]); acc1[0] = dot2bf(ud.x, wd1, acc1[0]);
            acc0[1] = dot2bf(ud.y, wd0, acc0[1]); acc1[1] = dot2bf(ud.y, wd1, acc1[1]);
            acc0[2] = dot2bf(ud.z, wd0, acc0[2]); acc1[2] = dot2bf(ud.z, wd1, acc1[2]);
            acc0[3] = dot2bf(ud.w, wd0, acc0[3]); acc1[3] = dot2bf(ud.w, wd1, acc1[3]);
#else
            float fa0 = bflo(wa), fa1 = bfhi(wa);
            float fb0 = bflo(wb), fb1 = bfhi(wb);
            float fc0 = bflo(wc), fc1 = bfhi(wc);
            float fd0 = bflo(wd), fd1 = bfhi(wd);
            acc0[0] += fa0 * bflo(ua.x); acc1[0] += fa1 * bfhi(ua.x);
            acc0[1] += fa0 * bflo(ua.y); acc1[1] += fa1 * bfhi(ua.y);
            acc0[2] += fa0 * bflo(ua.z); acc1[2] += fa1 * bfhi(ua.z);
            acc0[3] += fa0 * bflo(ua.w); acc1[3] += fa1 * bfhi(ua.w);
            acc0[0] += fb0 * bflo(ub.x); acc1[0] += fb1 * bfhi(ub.x);
            acc0[1] += fb0 * bflo(ub.y); acc1[1] += fb1 * bfhi(ub.y);
            acc0[2] += fb0 * bflo(ub.z); acc1[2] += fb1 * bfhi(ub.z);
            acc0[3] += fb0 * bflo(ub.w); acc1[3] += fb1 * bfhi(ub.w);
            acc0[0] += fc0 * bflo(uc.x); acc1[0] += fc1 * bfhi(uc.x);
            acc0[1] += fc0 * bflo(uc.y); acc1[1] += fc1 * bfhi(uc.y);
            acc0[2] += fc0 * bflo(uc.z); acc1[2] += fc1 * bfhi(uc.z);
            acc0[3] += fc0 * bflo(uc.w); acc1[3] += fc1 * bfhi(uc.w);
            acc0[0] += fd0 * bflo(ud.x); acc1[0] += fd1 * bfhi(ud.x);
            acc0[1] += fd0 * bflo(ud.y); acc1[1] += fd1 * bfhi(ud.y);
            acc0[2] += fd0 * bflo(ud.z); acc1[2] += fd1 * bfhi(ud.z);
            acc0[3] += fd0 * bflo(ud.w); acc1[3] += fd1 * bfhi(ud.w);
#endif
        }
    }

#pragma unroll
    for (int off = 1; off < 16; off <<= 1) {
        dsum0 += __shfl_xor(dsum0, off);
        dsum1 += __shfl_xor(dsum1, off);
    }
    float inv0 = dsum0 > 0.f ? 1.f / dsum0 : 0.f;
    float inv1 = dsum1 > 0.f ? 1.f / dsum1 : 0.f;

    if (!valid) return;

    float4 blo = *(const float4*)&bias[li * 4];
    float4 bhi = *(const float4*)&bias[64 + li * 4];
    float m0[4];
    m0[0] = (acc0[0] * inv0 + acc1[0] * inv1) * 0.5f + 0.5f * (blo.x + bhi.x);
    m0[1] = (acc0[1] * inv0 + acc1[1] * inv1) * 0.5f + 0.5f * (blo.y + bhi.y);
    m0[2] = (acc0[2] * inv0 + acc1[2] * inv1) * 0.5f + 0.5f * (blo.z + bhi.z);
    m0[3] = (acc0[3] * inv0 + acc1[3] * inv1) * 0.5f + 0.5f * (blo.w + bhi.w);

    if (do_ln) {
        float s = m0[0] + m0[1] + m0[2] + m0[3];
#pragma unroll
        for (int off = 1; off < 16; off <<= 1) s += __shfl_xor(s, off);
        float mu = s * (1.f / 64.f);
        float d0 = m0[0] - mu, d1 = m0[1] - mu, d2 = m0[2] - mu, d3 = m0[3] - mu;
        float v = d0 * d0 + d1 * d1 + d2 * d2 + d3 * d3;
#pragma unroll
        for (int off = 1; off < 16; off <<= 1) v += __shfl_xor(v, off);
        float rstd = rsqrtf(v * (1.f / 64.f) + 1e-5f);
        float4 g4 = *(const float4*)&gamma[li * 4];
        float4 be4 = *(const float4*)&beta[li * 4];
        float y0 = d0 * rstd * g4.x + be4.x;
        float y1 = d1 * rstd * g4.y + be4.y;
        float y2 = d2 * rstd * g4.z + be4.z;
        float y3 = d3 * rstd * g4.w + be4.w;
        y0 = y0 > 0.f ? y0 : 0.f;
        y1 = y1 > 0.f ? y1 : 0.f;
        y2 = y2 > 0.f ? y2 : 0.f;
        y3 = y3 > 0.f ? y3 : 0.f;
        ushort4 o = {(unsigned short)f2bf(y0), (unsigned short)f2bf(y1),
                     (unsigned short)f2bf(y2), (unsigned short)f2bf(y3)};
        *(ushort4*)&out_bf[(size_t)node * 64 + li * 4] = o;
    } else {
        *(float4*)&out_f[(size_t)node * 64 + li * 4] =
            make_float4(m0[0], m0[1], m0[2], m0[3]);
    }
}

// ---------------------------------------------------------------------------
static inline char* align_up(char* p, size_t a) {
    return (char*)(((uintptr_t)p + a - 1) & ~(uintptr_t)(a - 1));
}

extern "C" void kernel_launch(void* const* d_in, const int* in_sizes, int n_in,
                              void* d_out, int out_size, void* d_ws, size_t ws_size,
                              hipStream_t stream) {
    const float* feat = (const float*)d_in[0];
    const int* src = (const int*)d_in[1];
    const int* dst = (const int*)d_in[2];
    const float* W1 = (const float*)d_in[3];
    const float* al1 = (const float*)d_in[4];
    const float* ar1 = (const float*)d_in[5];
    const float* b1 = (const float*)d_in[6];
    const float* gamma1 = (const float*)d_in[7];
    const float* beta1 = (const float*)d_in[8];
    const float* W2 = (const float*)d_in[9];
    const float* al2 = (const float*)d_in[10];
    const float* ar2 = (const float*)d_in[11];
    const float* b2 = (const float*)d_in[12];

    const int N = in_sizes[0] / 128;
    const int E = in_sizes[1];
    const int B = (N + (1 << BKT_SHIFT) - 1) >> BKT_SHIFT;

    char* p = (char*)d_ws;
    p = align_up(p, 256);
    unsigned int* Zg = (unsigned int*)p;            p += (size_t)N * 64 * 4;
    float2* el2 = (float2*)p;                       p += (size_t)N * 8;
    float2* er2 = (float2*)p;                       p += (size_t)N * 8;
    int* row_start = (int*)p;                       p += (size_t)(N + 1) * 4;
    int* bucket_cnt = (int*)p;                      p += BKT_MAX * 4;
    int* bucket_start = (int*)p;                    p += (BKT_MAX + 1) * 4;
    int* bucket_cursor = (int*)p;                   p += BKT_MAX * 4;
    unsigned int* staging = (unsigned int*)p;       p += (size_t)E * 4;
    int* esrc = (int*)p;                            p += (size_t)E * 4;
    p = align_up(p, 64);
    unsigned short* hb = (unsigned short*)p;        p += (size_t)N * 64 * 2;
    p = align_up(p, 64);
    unsigned short* W1t = (unsigned short*)p;       p += 128 * 128 * 2;
    unsigned short* W2t = (unsigned short*)p;       p += 128 * 64 * 2;

    const int init_work = 128 * 128 + 64 * 128 + BKT_MAX;
    const int bin_blocks = (E + BIN_TPB * BIN_EPT - 1) / (BIN_TPB * BIN_EPT);

    init_small<<<(init_work + 255) / 256, 256, 0, stream>>>(W1, W1t, W2, W2t, bucket_cnt);
    hist_buckets<<<bin_blocks, BIN_TPB, 0, stream>>>(dst, bucket_cnt, E);
    scan_buckets<<<1, BKT_MAX, 0, stream>>>(bucket_cnt, bucket_start, bucket_cursor,
                                            row_start, B, N, E);
    bin_edges<<<bin_blocks, BIN_TPB, 0, stream>>>(src, dst, bucket_cursor, staging, E);
    build_csr<<<B, 256, 0, stream>>>(staging, bucket_start, row_start, esrc, N);

    // layer 0
    gemm_mfma<128, true><<<(N + 63) / 64, 256, 0, stream>>>(feat, W1t, al1, ar1,
                                                            Zg, el2, er2, N);
    aggregate<<<(N + 15) / 16, 256, 0, stream>>>((const uint4*)Zg, esrc, el2, er2,
                                                 row_start, b1, gamma1, beta1,
                                                 hb, nullptr, N, 1);

    // layer 1
    gemm_mfma<64, false><<<(N + 63) / 64, 256, 0, stream>>>(hb, W2t, al2, ar2,
                                                            Zg, el2, er2, N);
    aggregate<<<(N + 15) / 16, 256, 0, stream>>>((const uint4*)Zg, esrc, el2, er2,
                                                 row_start, b2, nullptr, nullptr,
                                                 nullptr, (float*)d_out, N, 0);
}